// Round 7
// baseline (431.527 us; speedup 1.0000x reference)
//
#include <hip/hip_runtime.h>

#define NN 100000
#define EE 500000
#define DD 64
#define OD 16
#define NR 6
#define NBASE 4
#define BSH 10
#define NBK 98         /* ceil(NN / 1024) */
#define SBLK 128       /* scatter blocks per relation */
#define FLATN (NBK * SBLK)   /* 12544 */
#define STCAP 5632     /* fine-bucket edge capacity (mean 5120 + 7 sigma) */

struct Edges { const int* src[NR]; const int* dst[NR]; };

__device__ __forceinline__ float bf2f(ushort u) {
    union { unsigned int i; float f; } v; v.i = ((unsigned int)u) << 16; return v.f;
}
__device__ __forceinline__ ushort f2bf(float f) {
    unsigned int x = __float_as_uint(f);
    unsigned int r = (x + 0x7fffu + ((x >> 16) & 1u)) >> 16;
    return (ushort)r;
}
__device__ __forceinline__ void bfpair(unsigned int u, float& lo, float& hi) {
    lo = __uint_as_float(u << 16);
    hi = __uint_as_float(u & 0xffff0000u);
}

// ---------------- W = einsum('rb,bio->rio') ----------------
__global__ __launch_bounds__(256) void build_w_kernel(
    const float* __restrict__ wc1, const float* __restrict__ b1,
    const float* __restrict__ wc2, const float* __restrict__ b2,
    float* __restrict__ W1, float* __restrict__ W2)
{
    int idx = blockIdx.x * blockDim.x + threadIdx.x;
    const int n1 = NR * DD * DD;
    const int n2 = NR * DD * OD;
    if (idx < n1) {
        int r = idx >> 12, rem = idx & 4095;
        float s = 0.f;
        #pragma unroll
        for (int b = 0; b < NBASE; ++b) s += wc1[r * NBASE + b] * b1[b * 4096 + rem];
        W1[idx] = s;
    } else if (idx < n1 + n2) {
        int j = idx - n1;
        int r = j >> 10, rem = j & 1023;
        float s = 0.f;
        #pragma unroll
        for (int b = 0; b < NBASE; ++b) s += wc2[r * NBASE + b] * b2[b * 1024 + rem];
        W2[j] = s;
    }
}

// ---------------- f32 -> bf16 embedding conversion ----------------
__global__ __launch_bounds__(256) void cvt_kernel(
    const float* __restrict__ in, ushort* __restrict__ out, int n4)
{
    int i = blockIdx.x * 256 + threadIdx.x;
    if (i >= n4) return;
    float4 v = ((const float4*)in)[i];
    ushort4 o;
    o.x = f2bf(v.x); o.y = f2bf(v.y); o.z = f2bf(v.z); o.w = f2bf(v.w);
    ((ushort4*)out)[i] = o;
}

// ---------------- CSR build: pass A — per-(block,bucket) counts ----------------
__global__ __launch_bounds__(256) void count_kernel(Edges ep, int* __restrict__ cnt_mat)
{
    __shared__ int h[NBK];
    int r = blockIdx.y, blk = blockIdx.x;
    const int* __restrict__ dst = ep.dst[r];
    const int chunk = (EE + SBLK - 1) / SBLK;
    int e0 = blk * chunk, e1 = min(e0 + chunk, EE);
    for (int i = threadIdx.x; i < NBK; i += 256) h[i] = 0;
    __syncthreads();
    for (int e = e0 + threadIdx.x; e < e1; e += 256)
        atomicAdd(&h[dst[e] >> BSH], 1);
    __syncthreads();
    for (int b = threadIdx.x; b < NBK; b += 256)
        cnt_mat[r * FLATN + b * SBLK + blk] = h[b];
}

// ---------------- pass B — flat exclusive scan over (bucket, block) per rel ----------------
__global__ __launch_bounds__(1024) void flat_scan_kernel(
    const int* __restrict__ cnt_mat, int* __restrict__ off_flat, int* __restrict__ bbase)
{
    __shared__ int wsum[16];
    const int TPE = 13;   /* 1024*13 = 13312 >= 12544 */
    int r = blockIdx.x;
    int tid = threadIdx.x, lane = tid & 63, wid = tid >> 6;
    int base = tid * TPE;
    int v[TPE];
    int s = 0;
    #pragma unroll
    for (int j = 0; j < TPE; ++j) {
        int i = base + j;
        v[j] = (i < FLATN) ? cnt_mat[r * FLATN + i] : 0;
        s += v[j];
    }
    int si = s;
    #pragma unroll
    for (int off = 1; off < 64; off <<= 1) {
        int t = __shfl_up(si, off);
        if (lane >= off) si += t;
    }
    if (lane == 63) wsum[wid] = si;
    __syncthreads();
    if (wid == 0) {
        int ws = (lane < 16) ? wsum[lane] : 0;
        #pragma unroll
        for (int off = 1; off < 16; off <<= 1) {
            int t = __shfl_up(ws, off);
            if (lane >= off) ws += t;
        }
        if (lane < 16) wsum[lane] = ws;
    }
    __syncthreads();
    int texcl = (wid > 0 ? wsum[wid - 1] : 0) + (si - s);
    int part = 0;
    #pragma unroll
    for (int j = 0; j < TPE; ++j) {
        int i = base + j;
        if (i < FLATN) {
            int o = texcl + part;
            off_flat[r * FLATN + i] = o;
            if ((i & (SBLK - 1)) == 0) bbase[r * (NBK + 1) + (i >> 7)] = o;
        }
        part += v[j];
    }
    if (tid == 0) bbase[r * (NBK + 1) + NBK] = EE;
}

// ---------------- pass C — scatter with precomputed cursors (no global atomics) ----------------
__global__ __launch_bounds__(256) void scatter2_kernel(
    Edges ep, const int* __restrict__ off_flat, unsigned int* __restrict__ ebuf)
{
    __shared__ int goff[NBK];
    __shared__ int lcnt[NBK];
    int r = blockIdx.y, blk = blockIdx.x;
    const int* __restrict__ src = ep.src[r];
    const int* __restrict__ dst = ep.dst[r];
    unsigned int* eb = ebuf + (size_t)r * EE;
    const int chunk = (EE + SBLK - 1) / SBLK;
    int e0 = blk * chunk, e1 = min(e0 + chunk, EE);
    if (threadIdx.x < NBK) {
        goff[threadIdx.x] = off_flat[r * FLATN + threadIdx.x * SBLK + blk];
        lcnt[threadIdx.x] = 0;
    }
    __syncthreads();
    for (int e = e0 + threadIdx.x; e < e1; e += 256) {
        int d = dst[e];
        int b = d >> BSH;
        int pos = goff[b] + atomicAdd(&lcnt[b], 1);
        eb[pos] = (unsigned int)src[e] | ((unsigned int)(d & 1023) << 17);
    }
}

// ---------------- pass D — per-(bucket,rel): row_ptr / inv_deg / col_idx for 1024 nodes ----------------
__global__ __launch_bounds__(256) void csr_fine_kernel(
    const unsigned int* __restrict__ ebuf, const int* __restrict__ bbase,
    int* __restrict__ row_ptr, float* __restrict__ inv_deg, int* __restrict__ col_idx)
{
    __shared__ int nh[1024];
    __shared__ int nb[1024];
    __shared__ int wsum4[4];
    __shared__ int stage[STCAP];
    int r = blockIdx.y, b = blockIdx.x;
    int tid = threadIdx.x, lane = tid & 63, wid = tid >> 6;
    int gb = bbase[r * (NBK + 1) + b];
    int ge = bbase[r * (NBK + 1) + b + 1];
    int cnt = ge - gb;
    if (cnt > STCAP) cnt = STCAP;   // statistically impossible; guard LDS
    const unsigned int* eb = ebuf + (size_t)r * EE + gb;
    #pragma unroll
    for (int j = 0; j < 4; ++j) nh[tid * 4 + j] = 0;
    __syncthreads();
    for (int i = tid; i < cnt; i += 256)
        atomicAdd(&nh[(eb[i] >> 17) & 1023], 1);
    __syncthreads();
    int v0 = nh[tid * 4 + 0], v1 = nh[tid * 4 + 1], v2 = nh[tid * 4 + 2], v3 = nh[tid * 4 + 3];
    int s = v0 + v1 + v2 + v3;
    int si = s;
    #pragma unroll
    for (int off = 1; off < 64; off <<= 1) {
        int t = __shfl_up(si, off);
        if (lane >= off) si += t;
    }
    if (lane == 63) wsum4[wid] = si;
    __syncthreads();
    if (tid == 0) {
        int a = 0;
        #pragma unroll
        for (int k = 0; k < 4; ++k) { int t = wsum4[k]; wsum4[k] = a; a += t; }
    }
    __syncthreads();
    int texcl = wsum4[wid] + (si - s);
    int p0 = texcl, p1 = p0 + v0, p2 = p1 + v1, p3 = p2 + v2;
    nb[tid * 4 + 0] = p0; nb[tid * 4 + 1] = p1; nb[tid * 4 + 2] = p2; nb[tid * 4 + 3] = p3;
    {
        int node0 = b * 1024 + tid * 4;
        int pj[4] = { p0, p1, p2, p3 };
        int vj[4] = { v0, v1, v2, v3 };
        #pragma unroll
        for (int j = 0; j < 4; ++j) {
            int node = node0 + j;
            if (node < NN) {
                row_ptr[r * (NN + 1) + node] = gb + pj[j];
                inv_deg[r * NN + node] = 1.0f / (float)(vj[j] > 1 ? vj[j] : 1);
            }
        }
    }
    if (b == NBK - 1 && tid == 0) row_ptr[r * (NN + 1) + NN] = EE;
    #pragma unroll
    for (int j = 0; j < 4; ++j) nh[tid * 4 + j] = 0;
    __syncthreads();
    for (int i = tid; i < cnt; i += 256) {
        unsigned int w = eb[i];
        int loc = (w >> 17) & 1023;
        int pos = nb[loc] + atomicAdd(&nh[loc], 1);
        stage[pos] = (int)(w & 0x1ffffu);
    }
    __syncthreads();
    int* co = col_idx + (size_t)r * EE + gb;
    for (int i = tid; i < cnt; i += 256) co[i] = stage[i];
}

// ---------------- layer-1/2 aggregation: 8 nodes per wave, 8 lanes per node ----------------
__global__ __launch_bounds__(256) void agg_kernel(
    const ushort* __restrict__ f0, const ushort* __restrict__ f1, const ushort* __restrict__ f2,
    int r0, int r1, int r2,
    const int* __restrict__ row_ptr, const int* __restrict__ col_idx,
    const float* __restrict__ inv_deg, ushort* __restrict__ z)
{
    int tid = threadIdx.x;
    int wid = tid >> 6, lane = tid & 63;
    int grp = lane >> 3;
    int sub = lane & 7;
    int n = blockIdx.x * 32 + wid * 8 + grp;
    int ks = blockIdx.y;
    const ushort* F = (ks == 0) ? f0 : ((ks == 1) ? f1 : f2);
    int r = (ks == 0) ? r0 : ((ks == 1) ? r1 : r2);
    const int* rp = row_ptr + r * (NN + 1);
    const int* ci = col_idx + (size_t)r * EE;
    bool valid = (n < NN);
    int s = valid ? rp[n] : 0;
    int e = valid ? rp[n + 1] : 0;
    float a0 = 0.f, a1 = 0.f, a2 = 0.f, a3 = 0.f, a4 = 0.f, a5 = 0.f, a6 = 0.f, a7 = 0.f;
    for (int t = s; t < e; ++t) {
        int c = ci[t];
        int4 v = *(const int4*)(F + (size_t)c * DD + sub * 8);
        float l0, h0, l1, h1, l2, h2, l3, h3;
        bfpair((unsigned int)v.x, l0, h0);
        bfpair((unsigned int)v.y, l1, h1);
        bfpair((unsigned int)v.z, l2, h2);
        bfpair((unsigned int)v.w, l3, h3);
        a0 += l0; a1 += h0; a2 += l1; a3 += h1;
        a4 += l2; a5 += h2; a6 += l3; a7 += h3;
    }
    if (valid) {
        float inv = inv_deg[r * NN + n];
        int4 o;
        o.x = (int)((unsigned int)f2bf(a0 * inv) | ((unsigned int)f2bf(a1 * inv) << 16));
        o.y = (int)((unsigned int)f2bf(a2 * inv) | ((unsigned int)f2bf(a3 * inv) << 16));
        o.z = (int)((unsigned int)f2bf(a4 * inv) | ((unsigned int)f2bf(a5 * inv) << 16));
        o.w = (int)((unsigned int)f2bf(a6 * inv) | ((unsigned int)f2bf(a7 * inv) << 16));
        *(int4*)(z + (size_t)n * 192 + ks * 64 + sub * 8) = o;
    }
}

// ---------------- fused layer-0: aggregate 3 rels + bias + relu -> h (bf16) ----------------
__global__ __launch_bounds__(256) void layer0_kernel(
    const ushort* __restrict__ f0, const ushort* __restrict__ f1, const ushort* __restrict__ f2,
    int r0, int r1, int r2,
    const int* __restrict__ row_ptr, const int* __restrict__ col_idx,
    const float* __restrict__ inv_deg, const float* __restrict__ bias,
    ushort* __restrict__ h)
{
    int tid = threadIdx.x;
    int wid = tid >> 6, lane = tid & 63;
    int grp = lane >> 3;
    int sub = lane & 7;
    int n = blockIdx.x * 32 + wid * 8 + grp;
    bool valid = (n < NN);
    float acc[8];
    {
        float4 b0 = *(const float4*)(bias + sub * 8);
        float4 b1 = *(const float4*)(bias + sub * 8 + 4);
        acc[0] = b0.x; acc[1] = b0.y; acc[2] = b0.z; acc[3] = b0.w;
        acc[4] = b1.x; acc[5] = b1.y; acc[6] = b1.z; acc[7] = b1.w;
    }
    #pragma unroll
    for (int ks = 0; ks < 3; ++ks) {
        const ushort* F = (ks == 0) ? f0 : ((ks == 1) ? f1 : f2);
        int r = (ks == 0) ? r0 : ((ks == 1) ? r1 : r2);
        const int* rp = row_ptr + r * (NN + 1);
        const int* ci = col_idx + (size_t)r * EE;
        int s = valid ? rp[n] : 0;
        int e = valid ? rp[n + 1] : 0;
        float a0 = 0.f, a1 = 0.f, a2 = 0.f, a3 = 0.f, a4 = 0.f, a5 = 0.f, a6 = 0.f, a7 = 0.f;
        for (int t = s; t < e; ++t) {
            int c = ci[t];
            int4 v = *(const int4*)(F + (size_t)c * DD + sub * 8);
            float l0, h0, l1, h1, l2, h2, l3, h3;
            bfpair((unsigned int)v.x, l0, h0);
            bfpair((unsigned int)v.y, l1, h1);
            bfpair((unsigned int)v.z, l2, h2);
            bfpair((unsigned int)v.w, l3, h3);
            a0 += l0; a1 += h0; a2 += l1; a3 += h1;
            a4 += l2; a5 += h2; a6 += l3; a7 += h3;
        }
        float inv = valid ? inv_deg[r * NN + n] : 0.f;
        acc[0] += a0 * inv; acc[1] += a1 * inv; acc[2] += a2 * inv; acc[3] += a3 * inv;
        acc[4] += a4 * inv; acc[5] += a5 * inv; acc[6] += a6 * inv; acc[7] += a7 * inv;
    }
    if (valid) {
        int4 o;
        o.x = (int)((unsigned int)f2bf(fmaxf(acc[0], 0.f)) | ((unsigned int)f2bf(fmaxf(acc[1], 0.f)) << 16));
        o.y = (int)((unsigned int)f2bf(fmaxf(acc[2], 0.f)) | ((unsigned int)f2bf(fmaxf(acc[3], 0.f)) << 16));
        o.z = (int)((unsigned int)f2bf(fmaxf(acc[4], 0.f)) | ((unsigned int)f2bf(fmaxf(acc[5], 0.f)) << 16));
        o.w = (int)((unsigned int)f2bf(fmaxf(acc[6], 0.f)) | ((unsigned int)f2bf(fmaxf(acc[7], 0.f)) << 16));
        *(int4*)(h + (size_t)n * DD + sub * 8) = o;
    }
}

// ---------------- tiled GEMM: out[M x NOUT] = z[M x 192] @ Wcat[192 x NOUT] ----------------
template<int NOUT, bool RELU, bool OUTBF16>
__global__ __launch_bounds__(256) void gemm_kernel(
    const ushort* __restrict__ A, const float* __restrict__ W,
    int r0, int r1, int r2, const float* __restrict__ bias, void* __restrict__ out)
{
    constexpr int ROWS = (NOUT == 64) ? 64 : 256;
    constexpr int RP = ROWS + 4;
    __shared__ float sA[32][RP];
    __shared__ float sW[32][NOUT];
    int tid = threadIdx.x;
    int rr[3] = { r0, r1, r2 };
    int nbase = blockIdx.x * ROWS;
    int c0, rt;
    if (NOUT == 64) { c0 = (tid & 15) * 4; rt = (tid >> 4) * 4; }
    else            { c0 = (tid & 3) * 4;  rt = (tid >> 2) * 4; }
    float acc[4][4] = {};
    for (int kb = 0; kb < 192; kb += 32) {
        for (int idx = tid; idx < ROWS * 16; idx += 256) {
            int row = idx >> 4, kp = (idx & 15) * 2;
            int n = nbase + row;
            unsigned int v = (n < NN) ? *(const unsigned int*)(A + (size_t)n * 192 + kb + kp) : 0u;
            sA[kp][row]     = bf2f((ushort)(v & 0xffffu));
            sA[kp + 1][row] = bf2f((ushort)(v >> 16));
        }
        for (int idx = tid; idx < 32 * NOUT; idx += 256) {
            int k = idx / NOUT, o = idx % NOUT;
            int g = kb + k;
            sW[k][o] = W[(size_t)rr[g >> 6] * (DD * NOUT) + (size_t)(g & 63) * NOUT + o];
        }
        __syncthreads();
        #pragma unroll
        for (int k = 0; k < 32; ++k) {
            float4 av = *(const float4*)&sA[k][rt];
            float4 wv = *(const float4*)&sW[k][c0];
            float a_[4] = { av.x, av.y, av.z, av.w };
            float w_[4] = { wv.x, wv.y, wv.z, wv.w };
            #pragma unroll
            for (int i = 0; i < 4; ++i)
                #pragma unroll
                for (int j = 0; j < 4; ++j)
                    acc[i][j] += a_[i] * w_[j];
        }
        __syncthreads();
    }
    #pragma unroll
    for (int i = 0; i < 4; ++i) {
        int n = nbase + rt + i;
        if (n >= NN) continue;
        if (OUTBF16) {
            ushort4 sv;
            float v0 = acc[i][0] + bias[c0 + 0];
            float v1 = acc[i][1] + bias[c0 + 1];
            float v2 = acc[i][2] + bias[c0 + 2];
            float v3 = acc[i][3] + bias[c0 + 3];
            if (RELU) { v0 = fmaxf(v0, 0.f); v1 = fmaxf(v1, 0.f); v2 = fmaxf(v2, 0.f); v3 = fmaxf(v3, 0.f); }
            sv.x = f2bf(v0); sv.y = f2bf(v1); sv.z = f2bf(v2); sv.w = f2bf(v3);
            *(ushort4*)&((ushort*)out)[(size_t)n * NOUT + c0] = sv;
        } else {
            float4 fv;
            fv.x = acc[i][0] + bias[c0 + 0];
            fv.y = acc[i][1] + bias[c0 + 1];
            fv.z = acc[i][2] + bias[c0 + 2];
            fv.w = acc[i][3] + bias[c0 + 3];
            if (RELU) { fv.x = fmaxf(fv.x, 0.f); fv.y = fmaxf(fv.y, 0.f); fv.z = fmaxf(fv.z, 0.f); fv.w = fmaxf(fv.w, 0.f); }
            *(float4*)&((float*)out)[(size_t)n * NOUT + c0] = fv;
        }
    }
}

extern "C" void kernel_launch(void* const* d_in, const int* in_sizes, int n_in,
                              void* d_out, int out_size, void* d_ws, size_t ws_size,
                              hipStream_t stream)
{
    const float* embA  = (const float*)d_in[0];
    const float* embB  = (const float*)d_in[1];
    const float* bias0 = (const float*)d_in[2];
    const float* wc1   = (const float*)d_in[3];
    const float* b1    = (const float*)d_in[4];
    const float* bias1 = (const float*)d_in[5];
    const float* wc2   = (const float*)d_in[6];
    const float* b2    = (const float*)d_in[7];
    const float* bias2 = (const float*)d_in[8];

    Edges ep;
    for (int r = 0; r < NR; ++r) {
        ep.src[r] = (const int*)d_in[9 + 2 * r];
        ep.dst[r] = (const int*)d_in[10 + 2 * r];
    }

    char* ws = (char*)d_ws;
    size_t off = 0;
    auto alloc = [&](size_t bytes) {
        void* p = ws + off;
        off = (off + bytes + 255) & ~(size_t)255;
        return p;
    };
    float*  W1      = (float*) alloc((size_t)NR * DD * DD * 4);
    float*  W2      = (float*) alloc((size_t)NR * DD * OD * 4);
    int*    cnt_mat = (int*)   alloc((size_t)NR * FLATN * 4);
    int*    off_fl  = (int*)   alloc((size_t)NR * FLATN * 4);
    int*    bbase   = (int*)   alloc((size_t)NR * (NBK + 1) * 4);
    int*    row_ptr = (int*)   alloc((size_t)NR * (NN + 1) * 4);
    float*  inv_deg = (float*) alloc((size_t)NR * NN * 4);
    int*    col_idx = (int*)   alloc((size_t)NR * EE * 4);
    ushort* zA      = (ushort*)alloc((size_t)NN * 192 * 2);
    ushort* zB      = (ushort*)alloc((size_t)NN * 192 * 2);
    ushort* h0A     = (ushort*)alloc((size_t)NN * DD * 2);
    ushort* h0B     = (ushort*)alloc((size_t)NN * DD * 2);
    ushort* h1A     = (ushort*)alloc((size_t)NN * DD * 2);
    ushort* h1B     = (ushort*)alloc((size_t)NN * DD * 2);
    (void)ws_size;

    // aliases (lifetime-disjoint):
    unsigned int* ebuf   = (unsigned int*)zA;  // used only before first agg write to zA
    ushort*       embA16 = h1A;                // used only during layer-0 agg
    ushort*       embB16 = h1B;

    int nw = NR * DD * DD + NR * DD * OD;
    build_w_kernel<<<(nw + 255) / 256, 256, 0, stream>>>(wc1, b1, wc2, b2, W1, W2);
    cvt_kernel<<<(NN * DD / 4 + 255) / 256, 256, 0, stream>>>(embA, embA16, NN * DD / 4);
    cvt_kernel<<<(NN * DD / 4 + 255) / 256, 256, 0, stream>>>(embB, embB16, NN * DD / 4);

    count_kernel<<<dim3(SBLK, NR), 256, 0, stream>>>(ep, cnt_mat);
    flat_scan_kernel<<<NR, 1024, 0, stream>>>(cnt_mat, off_fl, bbase);
    scatter2_kernel<<<dim3(SBLK, NR), 256, 0, stream>>>(ep, off_fl, ebuf);
    csr_fine_kernel<<<dim3(NBK, NR), 256, 0, stream>>>(ebuf, bbase, row_ptr, inv_deg, col_idx);

    dim3 agrid((NN + 31) / 32, 3);
    dim3 l0grid((NN + 31) / 32, 1);
    // relations: r0 A->B, r1 B->A, r2 A->A, r3 B->B, r4 A->B, r5 B->A
    // dst A: rels {1,2,5} srcs {B,A,B};  dst B: rels {0,3,4} srcs {A,B,A}

    // layer 0 (fused agg + bias + relu)
    layer0_kernel<<<l0grid, 256, 0, stream>>>(embB16, embA16, embB16, 1, 2, 5,
                                              row_ptr, col_idx, inv_deg, bias0, h0A);
    layer0_kernel<<<l0grid, 256, 0, stream>>>(embA16, embB16, embA16, 0, 3, 4,
                                              row_ptr, col_idx, inv_deg, bias0, h0B);

    // layer 1
    agg_kernel<<<agrid, 256, 0, stream>>>(h0B, h0A, h0B, 1, 2, 5,
                                          row_ptr, col_idx, inv_deg, zA);
    agg_kernel<<<agrid, 256, 0, stream>>>(h0A, h0B, h0A, 0, 3, 4,
                                          row_ptr, col_idx, inv_deg, zB);
    gemm_kernel<64, true, true><<<(NN + 63) / 64, 256, 0, stream>>>(
        zA, W1, 1, 2, 5, bias1, h1A);
    gemm_kernel<64, true, true><<<(NN + 63) / 64, 256, 0, stream>>>(
        zB, W1, 0, 3, 4, bias1, h1B);

    // layer 2 (only dst A needed)
    agg_kernel<<<agrid, 256, 0, stream>>>(h1B, h1A, h1B, 1, 2, 5,
                                          row_ptr, col_idx, inv_deg, zA);
    gemm_kernel<16, false, false><<<(NN + 255) / 256, 256, 0, stream>>>(
        zA, W2, 1, 2, 5, bias2, d_out);
}

// Round 8
// 333.176 us; speedup vs baseline: 1.2952x; 1.2952x over previous
//
#include <hip/hip_runtime.h>

#define NN 100000
#define EE 500000
#define DD 64
#define OD 16
#define NR 6
#define NBASE 4
#define BSH 10
#define NBK 98         /* ceil(NN / 1024) */
#define SBLK 128       /* scatter blocks per relation */
#define FLATN (NBK * SBLK)   /* 12544 */
#define STCAP 5632     /* fine-bucket edge capacity (mean 5120 + 7 sigma) */

struct Edges { const int* src[NR]; const int* dst[NR]; };

typedef __attribute__((ext_vector_type(8))) short bf16x8;
typedef __attribute__((ext_vector_type(4))) float f32x4;

__device__ __forceinline__ float bf2f(ushort u) {
    union { unsigned int i; float f; } v; v.i = ((unsigned int)u) << 16; return v.f;
}
__device__ __forceinline__ ushort f2bf(float f) {
    unsigned int x = __float_as_uint(f);
    unsigned int r = (x + 0x7fffu + ((x >> 16) & 1u)) >> 16;
    return (ushort)r;
}
__device__ __forceinline__ void bfpair(unsigned int u, float& lo, float& hi) {
    lo = __uint_as_float(u << 16);
    hi = __uint_as_float(u & 0xffff0000u);
}

// ---------------- W = einsum('rb,bio->rio'), emitted bf16 B-fragment-packed ----------------
// Wp1[((r*8 + i/8)*64 + o)*8 + i%8],  Wp2[((r*8 + i/8)*16 + o)*8 + i%8]
__global__ __launch_bounds__(256) void build_w_kernel(
    const float* __restrict__ wc1, const float* __restrict__ b1,
    const float* __restrict__ wc2, const float* __restrict__ b2,
    ushort* __restrict__ Wp1, ushort* __restrict__ Wp2)
{
    int idx = blockIdx.x * blockDim.x + threadIdx.x;
    const int n1 = NR * DD * DD;
    const int n2 = NR * DD * OD;
    if (idx < n1) {
        int r = idx >> 12, rem = idx & 4095;
        int i = rem >> 6, o = rem & 63;
        float s = 0.f;
        #pragma unroll
        for (int b = 0; b < NBASE; ++b) s += wc1[r * NBASE + b] * b1[b * 4096 + rem];
        Wp1[(((size_t)(r * 8 + (i >> 3)) * 64 + o) << 3) + (i & 7)] = f2bf(s);
    } else if (idx < n1 + n2) {
        int j = idx - n1;
        int r = j >> 10, rem = j & 1023;
        int i = rem >> 4, o = rem & 15;
        float s = 0.f;
        #pragma unroll
        for (int b = 0; b < NBASE; ++b) s += wc2[r * NBASE + b] * b2[b * 1024 + rem];
        Wp2[(((size_t)(r * 8 + (i >> 3)) * 16 + o) << 3) + (i & 7)] = f2bf(s);
    }
}

// ---------------- f32 -> bf16 embedding conversion ----------------
__global__ __launch_bounds__(256) void cvt_kernel(
    const float* __restrict__ in, ushort* __restrict__ out, int n4)
{
    int i = blockIdx.x * 256 + threadIdx.x;
    if (i >= n4) return;
    float4 v = ((const float4*)in)[i];
    ushort4 o;
    o.x = f2bf(v.x); o.y = f2bf(v.y); o.z = f2bf(v.z); o.w = f2bf(v.w);
    ((ushort4*)out)[i] = o;
}

// ---------------- CSR build: pass A — per-(block,bucket) counts ----------------
__global__ __launch_bounds__(256) void count_kernel(Edges ep, int* __restrict__ cnt_mat)
{
    __shared__ int h[NBK];
    int r = blockIdx.y, blk = blockIdx.x;
    const int* __restrict__ dst = ep.dst[r];
    const int chunk = (EE + SBLK - 1) / SBLK;
    int e0 = blk * chunk, e1 = min(e0 + chunk, EE);
    for (int i = threadIdx.x; i < NBK; i += 256) h[i] = 0;
    __syncthreads();
    for (int e = e0 + threadIdx.x; e < e1; e += 256)
        atomicAdd(&h[dst[e] >> BSH], 1);
    __syncthreads();
    for (int b = threadIdx.x; b < NBK; b += 256)
        cnt_mat[r * FLATN + b * SBLK + blk] = h[b];
}

// ---------------- pass B — flat exclusive scan over (bucket, block) per rel ----------------
__global__ __launch_bounds__(1024) void flat_scan_kernel(
    const int* __restrict__ cnt_mat, int* __restrict__ off_flat, int* __restrict__ bbase)
{
    __shared__ int wsum[16];
    const int TPE = 13;   /* 1024*13 = 13312 >= 12544 */
    int r = blockIdx.x;
    int tid = threadIdx.x, lane = tid & 63, wid = tid >> 6;
    int base = tid * TPE;
    int v[TPE];
    int s = 0;
    #pragma unroll
    for (int j = 0; j < TPE; ++j) {
        int i = base + j;
        v[j] = (i < FLATN) ? cnt_mat[r * FLATN + i] : 0;
        s += v[j];
    }
    int si = s;
    #pragma unroll
    for (int off = 1; off < 64; off <<= 1) {
        int t = __shfl_up(si, off);
        if (lane >= off) si += t;
    }
    if (lane == 63) wsum[wid] = si;
    __syncthreads();
    if (wid == 0) {
        int ws = (lane < 16) ? wsum[lane] : 0;
        #pragma unroll
        for (int off = 1; off < 16; off <<= 1) {
            int t = __shfl_up(ws, off);
            if (lane >= off) ws += t;
        }
        if (lane < 16) wsum[lane] = ws;
    }
    __syncthreads();
    int texcl = (wid > 0 ? wsum[wid - 1] : 0) + (si - s);
    int part = 0;
    #pragma unroll
    for (int j = 0; j < TPE; ++j) {
        int i = base + j;
        if (i < FLATN) {
            int o = texcl + part;
            off_flat[r * FLATN + i] = o;
            if ((i & (SBLK - 1)) == 0) bbase[r * (NBK + 1) + (i >> 7)] = o;
        }
        part += v[j];
    }
    if (tid == 0) bbase[r * (NBK + 1) + NBK] = EE;
}

// ---------------- pass C — scatter with precomputed cursors (no global atomics) ----------------
__global__ __launch_bounds__(256) void scatter2_kernel(
    Edges ep, const int* __restrict__ off_flat, unsigned int* __restrict__ ebuf)
{
    __shared__ int goff[NBK];
    __shared__ int lcnt[NBK];
    int r = blockIdx.y, blk = blockIdx.x;
    const int* __restrict__ src = ep.src[r];
    const int* __restrict__ dst = ep.dst[r];
    unsigned int* eb = ebuf + (size_t)r * EE;
    const int chunk = (EE + SBLK - 1) / SBLK;
    int e0 = blk * chunk, e1 = min(e0 + chunk, EE);
    if (threadIdx.x < NBK) {
        goff[threadIdx.x] = off_flat[r * FLATN + threadIdx.x * SBLK + blk];
        lcnt[threadIdx.x] = 0;
    }
    __syncthreads();
    for (int e = e0 + threadIdx.x; e < e1; e += 256) {
        int d = dst[e];
        int b = d >> BSH;
        int pos = goff[b] + atomicAdd(&lcnt[b], 1);
        eb[pos] = (unsigned int)src[e] | ((unsigned int)(d & 1023) << 17);
    }
}

// ---------------- pass D — per-(bucket,rel): row_ptr / inv_deg / col_idx for 1024 nodes ----------------
__global__ __launch_bounds__(256) void csr_fine_kernel(
    const unsigned int* __restrict__ ebuf, const int* __restrict__ bbase,
    int* __restrict__ row_ptr, float* __restrict__ inv_deg, int* __restrict__ col_idx)
{
    __shared__ int nh[1024];
    __shared__ int nb[1024];
    __shared__ int wsum4[4];
    __shared__ int stage[STCAP];
    int r = blockIdx.y, b = blockIdx.x;
    int tid = threadIdx.x, lane = tid & 63, wid = tid >> 6;
    int gb = bbase[r * (NBK + 1) + b];
    int ge = bbase[r * (NBK + 1) + b + 1];
    int cnt = ge - gb;
    if (cnt > STCAP) cnt = STCAP;   // statistically impossible; guard LDS
    const unsigned int* eb = ebuf + (size_t)r * EE + gb;
    #pragma unroll
    for (int j = 0; j < 4; ++j) nh[tid * 4 + j] = 0;
    __syncthreads();
    for (int i = tid; i < cnt; i += 256)
        atomicAdd(&nh[(eb[i] >> 17) & 1023], 1);
    __syncthreads();
    int v0 = nh[tid * 4 + 0], v1 = nh[tid * 4 + 1], v2 = nh[tid * 4 + 2], v3 = nh[tid * 4 + 3];
    int s = v0 + v1 + v2 + v3;
    int si = s;
    #pragma unroll
    for (int off = 1; off < 64; off <<= 1) {
        int t = __shfl_up(si, off);
        if (lane >= off) si += t;
    }
    if (lane == 63) wsum4[wid] = si;
    __syncthreads();
    if (tid == 0) {
        int a = 0;
        #pragma unroll
        for (int k = 0; k < 4; ++k) { int t = wsum4[k]; wsum4[k] = a; a += t; }
    }
    __syncthreads();
    int texcl = wsum4[wid] + (si - s);
    int p0 = texcl, p1 = p0 + v0, p2 = p1 + v1, p3 = p2 + v2;
    nb[tid * 4 + 0] = p0; nb[tid * 4 + 1] = p1; nb[tid * 4 + 2] = p2; nb[tid * 4 + 3] = p3;
    {
        int node0 = b * 1024 + tid * 4;
        int pj[4] = { p0, p1, p2, p3 };
        int vj[4] = { v0, v1, v2, v3 };
        #pragma unroll
        for (int j = 0; j < 4; ++j) {
            int node = node0 + j;
            if (node < NN) {
                row_ptr[r * (NN + 1) + node] = gb + pj[j];
                inv_deg[r * NN + node] = 1.0f / (float)(vj[j] > 1 ? vj[j] : 1);
            }
        }
    }
    if (b == NBK - 1 && tid == 0) row_ptr[r * (NN + 1) + NN] = EE;
    #pragma unroll
    for (int j = 0; j < 4; ++j) nh[tid * 4 + j] = 0;
    __syncthreads();
    for (int i = tid; i < cnt; i += 256) {
        unsigned int w = eb[i];
        int loc = (w >> 17) & 1023;
        int pos = nb[loc] + atomicAdd(&nh[loc], 1);
        stage[pos] = (int)(w & 0x1ffffu);
    }
    __syncthreads();
    int* co = col_idx + (size_t)r * EE + gb;
    for (int i = tid; i < cnt; i += 256) co[i] = stage[i];
}

// ---------------- layer-1/2 aggregation: 8 nodes per wave, 8 lanes per node ----------------
__global__ __launch_bounds__(256) void agg_kernel(
    const ushort* __restrict__ f0, const ushort* __restrict__ f1, const ushort* __restrict__ f2,
    int r0, int r1, int r2,
    const int* __restrict__ row_ptr, const int* __restrict__ col_idx,
    const float* __restrict__ inv_deg, ushort* __restrict__ z)
{
    int tid = threadIdx.x;
    int wid = tid >> 6, lane = tid & 63;
    int grp = lane >> 3;
    int sub = lane & 7;
    int n = blockIdx.x * 32 + wid * 8 + grp;
    int ks = blockIdx.y;
    const ushort* F = (ks == 0) ? f0 : ((ks == 1) ? f1 : f2);
    int r = (ks == 0) ? r0 : ((ks == 1) ? r1 : r2);
    const int* rp = row_ptr + r * (NN + 1);
    const int* ci = col_idx + (size_t)r * EE;
    bool valid = (n < NN);
    int s = valid ? rp[n] : 0;
    int e = valid ? rp[n + 1] : 0;
    float a0 = 0.f, a1 = 0.f, a2 = 0.f, a3 = 0.f, a4 = 0.f, a5 = 0.f, a6 = 0.f, a7 = 0.f;
    for (int t = s; t < e; ++t) {
        int c = ci[t];
        int4 v = *(const int4*)(F + (size_t)c * DD + sub * 8);
        float l0, h0, l1, h1, l2, h2, l3, h3;
        bfpair((unsigned int)v.x, l0, h0);
        bfpair((unsigned int)v.y, l1, h1);
        bfpair((unsigned int)v.z, l2, h2);
        bfpair((unsigned int)v.w, l3, h3);
        a0 += l0; a1 += h0; a2 += l1; a3 += h1;
        a4 += l2; a5 += h2; a6 += l3; a7 += h3;
    }
    if (valid) {
        float inv = inv_deg[r * NN + n];
        int4 o;
        o.x = (int)((unsigned int)f2bf(a0 * inv) | ((unsigned int)f2bf(a1 * inv) << 16));
        o.y = (int)((unsigned int)f2bf(a2 * inv) | ((unsigned int)f2bf(a3 * inv) << 16));
        o.z = (int)((unsigned int)f2bf(a4 * inv) | ((unsigned int)f2bf(a5 * inv) << 16));
        o.w = (int)((unsigned int)f2bf(a6 * inv) | ((unsigned int)f2bf(a7 * inv) << 16));
        *(int4*)(z + (size_t)n * 192 + ks * 64 + sub * 8) = o;
    }
}

// ---------------- fused layer-0: aggregate 3 rels + bias + relu -> h (bf16) ----------------
__global__ __launch_bounds__(256) void layer0_kernel(
    const ushort* __restrict__ f0, const ushort* __restrict__ f1, const ushort* __restrict__ f2,
    int r0, int r1, int r2,
    const int* __restrict__ row_ptr, const int* __restrict__ col_idx,
    const float* __restrict__ inv_deg, const float* __restrict__ bias,
    ushort* __restrict__ h)
{
    int tid = threadIdx.x;
    int wid = tid >> 6, lane = tid & 63;
    int grp = lane >> 3;
    int sub = lane & 7;
    int n = blockIdx.x * 32 + wid * 8 + grp;
    bool valid = (n < NN);
    float acc[8];
    {
        float4 b0 = *(const float4*)(bias + sub * 8);
        float4 b1 = *(const float4*)(bias + sub * 8 + 4);
        acc[0] = b0.x; acc[1] = b0.y; acc[2] = b0.z; acc[3] = b0.w;
        acc[4] = b1.x; acc[5] = b1.y; acc[6] = b1.z; acc[7] = b1.w;
    }
    #pragma unroll
    for (int ks = 0; ks < 3; ++ks) {
        const ushort* F = (ks == 0) ? f0 : ((ks == 1) ? f1 : f2);
        int r = (ks == 0) ? r0 : ((ks == 1) ? r1 : r2);
        const int* rp = row_ptr + r * (NN + 1);
        const int* ci = col_idx + (size_t)r * EE;
        int s = valid ? rp[n] : 0;
        int e = valid ? rp[n + 1] : 0;
        float a0 = 0.f, a1 = 0.f, a2 = 0.f, a3 = 0.f, a4 = 0.f, a5 = 0.f, a6 = 0.f, a7 = 0.f;
        for (int t = s; t < e; ++t) {
            int c = ci[t];
            int4 v = *(const int4*)(F + (size_t)c * DD + sub * 8);
            float l0, h0, l1, h1, l2, h2, l3, h3;
            bfpair((unsigned int)v.x, l0, h0);
            bfpair((unsigned int)v.y, l1, h1);
            bfpair((unsigned int)v.z, l2, h2);
            bfpair((unsigned int)v.w, l3, h3);
            a0 += l0; a1 += h0; a2 += l1; a3 += h1;
            a4 += l2; a5 += h2; a6 += l3; a7 += h3;
        }
        float inv = valid ? inv_deg[r * NN + n] : 0.f;
        acc[0] += a0 * inv; acc[1] += a1 * inv; acc[2] += a2 * inv; acc[3] += a3 * inv;
        acc[4] += a4 * inv; acc[5] += a5 * inv; acc[6] += a6 * inv; acc[7] += a7 * inv;
    }
    if (valid) {
        int4 o;
        o.x = (int)((unsigned int)f2bf(fmaxf(acc[0], 0.f)) | ((unsigned int)f2bf(fmaxf(acc[1], 0.f)) << 16));
        o.y = (int)((unsigned int)f2bf(fmaxf(acc[2], 0.f)) | ((unsigned int)f2bf(fmaxf(acc[3], 0.f)) << 16));
        o.z = (int)((unsigned int)f2bf(fmaxf(acc[4], 0.f)) | ((unsigned int)f2bf(fmaxf(acc[5], 0.f)) << 16));
        o.w = (int)((unsigned int)f2bf(fmaxf(acc[6], 0.f)) | ((unsigned int)f2bf(fmaxf(acc[7], 0.f)) << 16));
        *(int4*)(h + (size_t)n * DD + sub * 8) = o;
    }
}

// ---------------- layer-1 MFMA GEMM: h1 = relu(z @ Wcat + bias), bf16 out ----------------
// wave: 16 rows x 64 cols; lane q=lane&15 (A-row / B-col), p=lane>>4 (k-block)
__global__ __launch_bounds__(256) void gemm1_mfma_kernel(
    const ushort* __restrict__ A, const ushort* __restrict__ Wp,
    int r0, int r1, int r2, const float* __restrict__ bias, ushort* __restrict__ out)
{
    int tid = threadIdx.x;
    int wave = tid >> 6, lane = tid & 63;
    int q = lane & 15, p = lane >> 4;
    int n0 = blockIdx.x * 64 + wave * 16;
    int rr[3] = { r0, r1, r2 };
    f32x4 acc0 = {0.f, 0.f, 0.f, 0.f};
    f32x4 acc1 = {0.f, 0.f, 0.f, 0.f};
    f32x4 acc2 = {0.f, 0.f, 0.f, 0.f};
    f32x4 acc3 = {0.f, 0.f, 0.f, 0.f};
    const ushort* arow = A + (size_t)(n0 + q) * 192 + p * 8;
    #pragma unroll
    for (int ks = 0; ks < 3; ++ks) {
        int rel = rr[ks];
        #pragma unroll
        for (int t = 0; t < 2; ++t) {
            bf16x8 a = *(const bf16x8*)(arow + ks * 64 + t * 32);
            const ushort* wb = Wp + (((size_t)(rel * 8 + t * 4 + p) * 64 + q) << 3);
            bf16x8 b0 = *(const bf16x8*)(wb);
            bf16x8 b1 = *(const bf16x8*)(wb + 16 * 8);
            bf16x8 b2 = *(const bf16x8*)(wb + 32 * 8);
            bf16x8 b3 = *(const bf16x8*)(wb + 48 * 8);
            acc0 = __builtin_amdgcn_mfma_f32_16x16x32_bf16(a, b0, acc0, 0, 0, 0);
            acc1 = __builtin_amdgcn_mfma_f32_16x16x32_bf16(a, b1, acc1, 0, 0, 0);
            acc2 = __builtin_amdgcn_mfma_f32_16x16x32_bf16(a, b2, acc2, 0, 0, 0);
            acc3 = __builtin_amdgcn_mfma_f32_16x16x32_bf16(a, b3, acc3, 0, 0, 0);
        }
    }
    float bv0 = bias[q], bv1 = bias[16 + q], bv2 = bias[32 + q], bv3 = bias[48 + q];
    #pragma unroll
    for (int v = 0; v < 4; ++v) {
        int n = n0 + p * 4 + v;
        if (n < NN) {
            ushort* orow = out + (size_t)n * 64;
            orow[q]      = f2bf(fmaxf(acc0[v] + bv0, 0.f));
            orow[16 + q] = f2bf(fmaxf(acc1[v] + bv1, 0.f));
            orow[32 + q] = f2bf(fmaxf(acc2[v] + bv2, 0.f));
            orow[48 + q] = f2bf(fmaxf(acc3[v] + bv3, 0.f));
        }
    }
}

// ---------------- layer-2 MFMA GEMM: out = z @ Wcat2 + bias2, f32 out ----------------
__global__ __launch_bounds__(256) void gemm2_mfma_kernel(
    const ushort* __restrict__ A, const ushort* __restrict__ Wp,
    int r0, int r1, int r2, const float* __restrict__ bias, float* __restrict__ out)
{
    int tid = threadIdx.x;
    int wave = tid >> 6, lane = tid & 63;
    int q = lane & 15, p = lane >> 4;
    int n0 = blockIdx.x * 64 + wave * 16;
    int rr[3] = { r0, r1, r2 };
    f32x4 acc = {0.f, 0.f, 0.f, 0.f};
    const ushort* arow = A + (size_t)(n0 + q) * 192 + p * 8;
    #pragma unroll
    for (int ks = 0; ks < 3; ++ks) {
        int rel = rr[ks];
        #pragma unroll
        for (int t = 0; t < 2; ++t) {
            bf16x8 a = *(const bf16x8*)(arow + ks * 64 + t * 32);
            bf16x8 b = *(const bf16x8*)(Wp + (((size_t)(rel * 8 + t * 4 + p) * 16 + q) << 3));
            acc = __builtin_amdgcn_mfma_f32_16x16x32_bf16(a, b, acc, 0, 0, 0);
        }
    }
    float bv = bias[q];
    #pragma unroll
    for (int v = 0; v < 4; ++v) {
        int n = n0 + p * 4 + v;
        if (n < NN) out[(size_t)n * 16 + q] = acc[v] + bv;
    }
}

extern "C" void kernel_launch(void* const* d_in, const int* in_sizes, int n_in,
                              void* d_out, int out_size, void* d_ws, size_t ws_size,
                              hipStream_t stream)
{
    const float* embA  = (const float*)d_in[0];
    const float* embB  = (const float*)d_in[1];
    const float* bias0 = (const float*)d_in[2];
    const float* wc1   = (const float*)d_in[3];
    const float* b1    = (const float*)d_in[4];
    const float* bias1 = (const float*)d_in[5];
    const float* wc2   = (const float*)d_in[6];
    const float* b2    = (const float*)d_in[7];
    const float* bias2 = (const float*)d_in[8];

    Edges ep;
    for (int r = 0; r < NR; ++r) {
        ep.src[r] = (const int*)d_in[9 + 2 * r];
        ep.dst[r] = (const int*)d_in[10 + 2 * r];
    }

    char* ws = (char*)d_ws;
    size_t off = 0;
    auto alloc = [&](size_t bytes) {
        void* p = ws + off;
        off = (off + bytes + 255) & ~(size_t)255;
        return p;
    };
    ushort* Wp1     = (ushort*)alloc((size_t)NR * 8 * 64 * 8 * 2);
    ushort* Wp2     = (ushort*)alloc((size_t)NR * 8 * 16 * 8 * 2);
    int*    cnt_mat = (int*)   alloc((size_t)NR * FLATN * 4);
    int*    off_fl  = (int*)   alloc((size_t)NR * FLATN * 4);
    int*    bbase   = (int*)   alloc((size_t)NR * (NBK + 1) * 4);
    int*    row_ptr = (int*)   alloc((size_t)NR * (NN + 1) * 4);
    float*  inv_deg = (float*) alloc((size_t)NR * NN * 4);
    int*    col_idx = (int*)   alloc((size_t)NR * EE * 4);
    ushort* zA      = (ushort*)alloc((size_t)NN * 192 * 2);
    ushort* zB      = (ushort*)alloc((size_t)NN * 192 * 2);
    ushort* h0A     = (ushort*)alloc((size_t)NN * DD * 2);
    ushort* h0B     = (ushort*)alloc((size_t)NN * DD * 2);
    ushort* h1A     = (ushort*)alloc((size_t)NN * DD * 2);
    ushort* h1B     = (ushort*)alloc((size_t)NN * DD * 2);
    (void)ws_size;

    // aliases (lifetime-disjoint):
    unsigned int* ebuf   = (unsigned int*)zA;  // used only before first agg write to zA
    ushort*       embA16 = h1A;                // used only during layer-0 agg
    ushort*       embB16 = h1B;

    int nw = NR * DD * DD + NR * DD * OD;
    build_w_kernel<<<(nw + 255) / 256, 256, 0, stream>>>(wc1, b1, wc2, b2, Wp1, Wp2);
    cvt_kernel<<<(NN * DD / 4 + 255) / 256, 256, 0, stream>>>(embA, embA16, NN * DD / 4);
    cvt_kernel<<<(NN * DD / 4 + 255) / 256, 256, 0, stream>>>(embB, embB16, NN * DD / 4);

    count_kernel<<<dim3(SBLK, NR), 256, 0, stream>>>(ep, cnt_mat);
    flat_scan_kernel<<<NR, 1024, 0, stream>>>(cnt_mat, off_fl, bbase);
    scatter2_kernel<<<dim3(SBLK, NR), 256, 0, stream>>>(ep, off_fl, ebuf);
    csr_fine_kernel<<<dim3(NBK, NR), 256, 0, stream>>>(ebuf, bbase, row_ptr, inv_deg, col_idx);

    dim3 agrid((NN + 31) / 32, 3);
    dim3 l0grid((NN + 31) / 32, 1);
    int ggrid = (NN + 63) / 64;
    // relations: r0 A->B, r1 B->A, r2 A->A, r3 B->B, r4 A->B, r5 B->A
    // dst A: rels {1,2,5} srcs {B,A,B};  dst B: rels {0,3,4} srcs {A,B,A}

    // layer 0 (fused agg + bias + relu)
    layer0_kernel<<<l0grid, 256, 0, stream>>>(embB16, embA16, embB16, 1, 2, 5,
                                              row_ptr, col_idx, inv_deg, bias0, h0A);
    layer0_kernel<<<l0grid, 256, 0, stream>>>(embA16, embB16, embA16, 0, 3, 4,
                                              row_ptr, col_idx, inv_deg, bias0, h0B);

    // layer 1
    agg_kernel<<<agrid, 256, 0, stream>>>(h0B, h0A, h0B, 1, 2, 5,
                                          row_ptr, col_idx, inv_deg, zA);
    agg_kernel<<<agrid, 256, 0, stream>>>(h0A, h0B, h0A, 0, 3, 4,
                                          row_ptr, col_idx, inv_deg, zB);
    gemm1_mfma_kernel<<<ggrid, 256, 0, stream>>>(zA, Wp1, 1, 2, 5, bias1, h1A);
    gemm1_mfma_kernel<<<ggrid, 256, 0, stream>>>(zB, Wp1, 0, 3, 4, bias1, h1B);

    // layer 2 (only dst A needed)
    agg_kernel<<<agrid, 256, 0, stream>>>(h1B, h1A, h1B, 1, 2, 5,
                                          row_ptr, col_idx, inv_deg, zA);
    gemm2_mfma_kernel<<<ggrid, 256, 0, stream>>>(zA, Wp2, 1, 2, 5, bias2, (float*)d_out);
}

// Round 9
// 310.692 us; speedup vs baseline: 1.3889x; 1.0724x over previous
//
#include <hip/hip_runtime.h>

#define NN 100000
#define EE 500000
#define DD 64
#define OD 16
#define NR 6
#define NBASE 4
#define BSH 10
#define NBK 98         /* ceil(NN / 1024) */
#define SBLK 128       /* scatter blocks per relation */
#define FLATN (NBK * SBLK)   /* 12544 */
#define STCAP 5632     /* fine-bucket edge capacity */
#define DBIN 64        /* degree-sort bins */
#define DBLK 128       /* degree-sort blocks per vrel */
#define FLAT2 (DBIN * DBLK)  /* 8192 */
#define NVR 8          /* 6 per-rel orders + 2 sum-degree orders */

struct Edges { const int* src[NR]; const int* dst[NR]; };

typedef __attribute__((ext_vector_type(8))) short bf16x8;
typedef __attribute__((ext_vector_type(4))) float f32x4;

__device__ __forceinline__ float bf2f(ushort u) {
    union { unsigned int i; float f; } v; v.i = ((unsigned int)u) << 16; return v.f;
}
__device__ __forceinline__ ushort f2bf(float f) {
    unsigned int x = __float_as_uint(f);
    unsigned int r = (x + 0x7fffu + ((x >> 16) & 1u)) >> 16;
    return (ushort)r;
}
__device__ __forceinline__ void bfpair(unsigned int u, float& lo, float& hi) {
    lo = __uint_as_float(u << 16);
    hi = __uint_as_float(u & 0xffff0000u);
}

// ---------------- W = einsum('rb,bio->rio'), emitted bf16 B-fragment-packed ----------------
__global__ __launch_bounds__(256) void build_w_kernel(
    const float* __restrict__ wc1, const float* __restrict__ b1,
    const float* __restrict__ wc2, const float* __restrict__ b2,
    ushort* __restrict__ Wp1, ushort* __restrict__ Wp2)
{
    int idx = blockIdx.x * blockDim.x + threadIdx.x;
    const int n1 = NR * DD * DD;
    const int n2 = NR * DD * OD;
    if (idx < n1) {
        int r = idx >> 12, rem = idx & 4095;
        int i = rem >> 6, o = rem & 63;
        float s = 0.f;
        #pragma unroll
        for (int b = 0; b < NBASE; ++b) s += wc1[r * NBASE + b] * b1[b * 4096 + rem];
        Wp1[(((size_t)(r * 8 + (i >> 3)) * 64 + o) << 3) + (i & 7)] = f2bf(s);
    } else if (idx < n1 + n2) {
        int j = idx - n1;
        int r = j >> 10, rem = j & 1023;
        int i = rem >> 4, o = rem & 15;
        float s = 0.f;
        #pragma unroll
        for (int b = 0; b < NBASE; ++b) s += wc2[r * NBASE + b] * b2[b * 1024 + rem];
        Wp2[(((size_t)(r * 8 + (i >> 3)) * 16 + o) << 3) + (i & 7)] = f2bf(s);
    }
}

// ---------------- f32 -> bf16 embedding conversion ----------------
__global__ __launch_bounds__(256) void cvt_kernel(
    const float* __restrict__ in, ushort* __restrict__ out, int n4)
{
    int i = blockIdx.x * 256 + threadIdx.x;
    if (i >= n4) return;
    float4 v = ((const float4*)in)[i];
    ushort4 o;
    o.x = f2bf(v.x); o.y = f2bf(v.y); o.z = f2bf(v.z); o.w = f2bf(v.w);
    ((ushort4*)out)[i] = o;
}

// ---------------- CSR build: pass A — per-(block,bucket) counts ----------------
__global__ __launch_bounds__(256) void count_kernel(Edges ep, int* __restrict__ cnt_mat)
{
    __shared__ int h[NBK];
    int r = blockIdx.y, blk = blockIdx.x;
    const int* __restrict__ dst = ep.dst[r];
    const int chunk = (EE + SBLK - 1) / SBLK;
    int e0 = blk * chunk, e1 = min(e0 + chunk, EE);
    for (int i = threadIdx.x; i < NBK; i += 256) h[i] = 0;
    __syncthreads();
    for (int e = e0 + threadIdx.x; e < e1; e += 256)
        atomicAdd(&h[dst[e] >> BSH], 1);
    __syncthreads();
    for (int b = threadIdx.x; b < NBK; b += 256)
        cnt_mat[r * FLATN + b * SBLK + blk] = h[b];
}

// ---------------- pass B — flat exclusive scan over (bucket, block) per rel ----------------
__global__ __launch_bounds__(1024) void flat_scan_kernel(
    const int* __restrict__ cnt_mat, int* __restrict__ off_flat, int* __restrict__ bbase)
{
    __shared__ int wsum[16];
    const int TPE = 13;
    int r = blockIdx.x;
    int tid = threadIdx.x, lane = tid & 63, wid = tid >> 6;
    int base = tid * TPE;
    int v[TPE];
    int s = 0;
    #pragma unroll
    for (int j = 0; j < TPE; ++j) {
        int i = base + j;
        v[j] = (i < FLATN) ? cnt_mat[r * FLATN + i] : 0;
        s += v[j];
    }
    int si = s;
    #pragma unroll
    for (int off = 1; off < 64; off <<= 1) {
        int t = __shfl_up(si, off);
        if (lane >= off) si += t;
    }
    if (lane == 63) wsum[wid] = si;
    __syncthreads();
    if (wid == 0) {
        int ws = (lane < 16) ? wsum[lane] : 0;
        #pragma unroll
        for (int off = 1; off < 16; off <<= 1) {
            int t = __shfl_up(ws, off);
            if (lane >= off) ws += t;
        }
        if (lane < 16) wsum[lane] = ws;
    }
    __syncthreads();
    int texcl = (wid > 0 ? wsum[wid - 1] : 0) + (si - s);
    int part = 0;
    #pragma unroll
    for (int j = 0; j < TPE; ++j) {
        int i = base + j;
        if (i < FLATN) {
            int o = texcl + part;
            off_flat[r * FLATN + i] = o;
            if ((i & (SBLK - 1)) == 0) bbase[r * (NBK + 1) + (i >> 7)] = o;
        }
        part += v[j];
    }
    if (tid == 0) bbase[r * (NBK + 1) + NBK] = EE;
}

// ---------------- pass C — scatter with precomputed cursors ----------------
__global__ __launch_bounds__(256) void scatter2_kernel(
    Edges ep, const int* __restrict__ off_flat, unsigned int* __restrict__ ebuf)
{
    __shared__ int goff[NBK];
    __shared__ int lcnt[NBK];
    int r = blockIdx.y, blk = blockIdx.x;
    const int* __restrict__ src = ep.src[r];
    const int* __restrict__ dst = ep.dst[r];
    unsigned int* eb = ebuf + (size_t)r * EE;
    const int chunk = (EE + SBLK - 1) / SBLK;
    int e0 = blk * chunk, e1 = min(e0 + chunk, EE);
    if (threadIdx.x < NBK) {
        goff[threadIdx.x] = off_flat[r * FLATN + threadIdx.x * SBLK + blk];
        lcnt[threadIdx.x] = 0;
    }
    __syncthreads();
    for (int e = e0 + threadIdx.x; e < e1; e += 256) {
        int d = dst[e];
        int b = d >> BSH;
        int pos = goff[b] + atomicAdd(&lcnt[b], 1);
        eb[pos] = (unsigned int)src[e] | ((unsigned int)(d & 1023) << 17);
    }
}

// ---------------- pass D — per-(bucket,rel) fine CSR ----------------
__global__ __launch_bounds__(256) void csr_fine_kernel(
    const unsigned int* __restrict__ ebuf, const int* __restrict__ bbase,
    int* __restrict__ row_ptr, float* __restrict__ inv_deg, int* __restrict__ col_idx)
{
    __shared__ int nh[1024];
    __shared__ int nb[1024];
    __shared__ int wsum4[4];
    __shared__ int stage[STCAP];
    int r = blockIdx.y, b = blockIdx.x;
    int tid = threadIdx.x, lane = tid & 63, wid = tid >> 6;
    int gb = bbase[r * (NBK + 1) + b];
    int ge = bbase[r * (NBK + 1) + b + 1];
    int cnt = ge - gb;
    if (cnt > STCAP) cnt = STCAP;
    const unsigned int* eb = ebuf + (size_t)r * EE + gb;
    #pragma unroll
    for (int j = 0; j < 4; ++j) nh[tid * 4 + j] = 0;
    __syncthreads();
    for (int i = tid; i < cnt; i += 256)
        atomicAdd(&nh[(eb[i] >> 17) & 1023], 1);
    __syncthreads();
    int v0 = nh[tid * 4 + 0], v1 = nh[tid * 4 + 1], v2 = nh[tid * 4 + 2], v3 = nh[tid * 4 + 3];
    int s = v0 + v1 + v2 + v3;
    int si = s;
    #pragma unroll
    for (int off = 1; off < 64; off <<= 1) {
        int t = __shfl_up(si, off);
        if (lane >= off) si += t;
    }
    if (lane == 63) wsum4[wid] = si;
    __syncthreads();
    if (tid == 0) {
        int a = 0;
        #pragma unroll
        for (int k = 0; k < 4; ++k) { int t = wsum4[k]; wsum4[k] = a; a += t; }
    }
    __syncthreads();
    int texcl = wsum4[wid] + (si - s);
    int p0 = texcl, p1 = p0 + v0, p2 = p1 + v1, p3 = p2 + v2;
    nb[tid * 4 + 0] = p0; nb[tid * 4 + 1] = p1; nb[tid * 4 + 2] = p2; nb[tid * 4 + 3] = p3;
    {
        int node0 = b * 1024 + tid * 4;
        int pj[4] = { p0, p1, p2, p3 };
        int vj[4] = { v0, v1, v2, v3 };
        #pragma unroll
        for (int j = 0; j < 4; ++j) {
            int node = node0 + j;
            if (node < NN) {
                row_ptr[r * (NN + 1) + node] = gb + pj[j];
                inv_deg[r * NN + node] = 1.0f / (float)(vj[j] > 1 ? vj[j] : 1);
            }
        }
    }
    if (b == NBK - 1 && tid == 0) row_ptr[r * (NN + 1) + NN] = EE;
    #pragma unroll
    for (int j = 0; j < 4; ++j) nh[tid * 4 + j] = 0;
    __syncthreads();
    for (int i = tid; i < cnt; i += 256) {
        unsigned int w = eb[i];
        int loc = (w >> 17) & 1023;
        int pos = nb[loc] + atomicAdd(&nh[loc], 1);
        stage[pos] = (int)(w & 0x1ffffu);
    }
    __syncthreads();
    int* co = col_idx + (size_t)r * EE + gb;
    for (int i = tid; i < cnt; i += 256) co[i] = stage[i];
}

// ---------------- degree-sort: virtual rel 0..5 = rel degree, 6/7 = sum-degree dstA/dstB ----------------
__device__ __forceinline__ int vdeg(int vr, int n, const int* __restrict__ rp)
{
    if (vr < 6) return rp[vr * (NN + 1) + n + 1] - rp[vr * (NN + 1) + n];
    if (vr == 6)
        return (rp[1 * (NN + 1) + n + 1] - rp[1 * (NN + 1) + n])
             + (rp[2 * (NN + 1) + n + 1] - rp[2 * (NN + 1) + n])
             + (rp[5 * (NN + 1) + n + 1] - rp[5 * (NN + 1) + n]);
    return (rp[0 * (NN + 1) + n + 1] - rp[0 * (NN + 1) + n])
         + (rp[3 * (NN + 1) + n + 1] - rp[3 * (NN + 1) + n])
         + (rp[4 * (NN + 1) + n + 1] - rp[4 * (NN + 1) + n]);
}

__global__ __launch_bounds__(256) void dhist_kernel(
    const int* __restrict__ row_ptr, int* __restrict__ cnt2)
{
    __shared__ int h[DBIN];
    int vr = blockIdx.y, blk = blockIdx.x;
    if (threadIdx.x < DBIN) h[threadIdx.x] = 0;
    __syncthreads();
    const int chunk = (NN + DBLK - 1) / DBLK;
    int n0 = blk * chunk, n1 = min(n0 + chunk, NN);
    for (int n = n0 + threadIdx.x; n < n1; n += 256)
        atomicAdd(&h[min(vdeg(vr, n, row_ptr), DBIN - 1)], 1);
    __syncthreads();
    if (threadIdx.x < DBIN) cnt2[vr * FLAT2 + threadIdx.x * DBLK + blk] = h[threadIdx.x];
}

__global__ __launch_bounds__(1024) void dscan_kernel(
    const int* __restrict__ cnt2, int* __restrict__ off2)
{
    __shared__ int wsum[16];
    const int TPE = 8;   /* 1024*8 = 8192 */
    int vr = blockIdx.x;
    int tid = threadIdx.x, lane = tid & 63, wid = tid >> 6;
    int base = tid * TPE;
    int v[TPE];
    int s = 0;
    #pragma unroll
    for (int j = 0; j < TPE; ++j) { v[j] = cnt2[vr * FLAT2 + base + j]; s += v[j]; }
    int si = s;
    #pragma unroll
    for (int off = 1; off < 64; off <<= 1) {
        int t = __shfl_up(si, off);
        if (lane >= off) si += t;
    }
    if (lane == 63) wsum[wid] = si;
    __syncthreads();
    if (wid == 0) {
        int ws = (lane < 16) ? wsum[lane] : 0;
        #pragma unroll
        for (int off = 1; off < 16; off <<= 1) {
            int t = __shfl_up(ws, off);
            if (lane >= off) ws += t;
        }
        if (lane < 16) wsum[lane] = ws;
    }
    __syncthreads();
    int texcl = (wid > 0 ? wsum[wid - 1] : 0) + (si - s);
    int part = 0;
    #pragma unroll
    for (int j = 0; j < TPE; ++j) {
        off2[vr * FLAT2 + base + j] = texcl + part;
        part += v[j];
    }
}

__global__ __launch_bounds__(256) void dscatter_kernel(
    const int* __restrict__ row_ptr, const int* __restrict__ off2, int* __restrict__ perm)
{
    __shared__ int goff[DBIN];
    __shared__ int lcnt[DBIN];
    int vr = blockIdx.y, blk = blockIdx.x;
    if (threadIdx.x < DBIN) {
        goff[threadIdx.x] = off2[vr * FLAT2 + threadIdx.x * DBLK + blk];
        lcnt[threadIdx.x] = 0;
    }
    __syncthreads();
    const int chunk = (NN + DBLK - 1) / DBLK;
    int n0 = blk * chunk, n1 = min(n0 + chunk, NN);
    for (int n = n0 + threadIdx.x; n < n1; n += 256) {
        int b = min(vdeg(vr, n, row_ptr), DBIN - 1);
        int pos = goff[b] + atomicAdd(&lcnt[b], 1);
        perm[vr * NN + pos] = n;
    }
}

// ---------------- merged aggregation (layers 1/2): y -> (dst side, rel slot) ----------------
// y<3: dst A, rels {1,2,5}, srcs {B,A,B}, out zA; y>=3: dst B, rels {0,3,4}, srcs {A,B,A}, out zB
__global__ __launch_bounds__(256) void agg_kernel(
    const ushort* __restrict__ hA, const ushort* __restrict__ hB,
    const int* __restrict__ row_ptr, const int* __restrict__ col_idx,
    const float* __restrict__ inv_deg, const int* __restrict__ perm,
    ushort* __restrict__ zA, ushort* __restrict__ zB)
{
    const int relT[6]   = {1, 2, 5, 0, 3, 4};
    const int srcIsA[6] = {0, 1, 0, 1, 0, 1};
    int y = blockIdx.y;
    int r = relT[y];
    const ushort* F = srcIsA[y] ? hA : hB;
    ushort* z = (y < 3) ? zA : zB;
    int ks = (y < 3) ? y : y - 3;
    int tid = threadIdx.x;
    int wid = tid >> 6, lane = tid & 63;
    int grp = lane >> 3, sub = lane & 7;
    int idx = blockIdx.x * 32 + wid * 8 + grp;
    bool valid = (idx < NN);
    int n = valid ? perm[r * NN + idx] : 0;
    const int* rp = row_ptr + r * (NN + 1);
    const int* ci = col_idx + (size_t)r * EE;
    int s = valid ? rp[n] : 0;
    int e = valid ? rp[n + 1] : 0;
    float a0 = 0.f, a1 = 0.f, a2 = 0.f, a3 = 0.f, a4 = 0.f, a5 = 0.f, a6 = 0.f, a7 = 0.f;
    int t = s;
    for (; t + 2 <= e; t += 2) {
        int c0 = ci[t], c1 = ci[t + 1];
        int4 u = *(const int4*)(F + (size_t)c0 * DD + sub * 8);
        int4 w = *(const int4*)(F + (size_t)c1 * DD + sub * 8);
        float l, h;
        bfpair((unsigned int)u.x, l, h); a0 += l; a1 += h;
        bfpair((unsigned int)u.y, l, h); a2 += l; a3 += h;
        bfpair((unsigned int)u.z, l, h); a4 += l; a5 += h;
        bfpair((unsigned int)u.w, l, h); a6 += l; a7 += h;
        bfpair((unsigned int)w.x, l, h); a0 += l; a1 += h;
        bfpair((unsigned int)w.y, l, h); a2 += l; a3 += h;
        bfpair((unsigned int)w.z, l, h); a4 += l; a5 += h;
        bfpair((unsigned int)w.w, l, h); a6 += l; a7 += h;
    }
    if (t < e) {
        int c0 = ci[t];
        int4 u = *(const int4*)(F + (size_t)c0 * DD + sub * 8);
        float l, h;
        bfpair((unsigned int)u.x, l, h); a0 += l; a1 += h;
        bfpair((unsigned int)u.y, l, h); a2 += l; a3 += h;
        bfpair((unsigned int)u.z, l, h); a4 += l; a5 += h;
        bfpair((unsigned int)u.w, l, h); a6 += l; a7 += h;
    }
    if (valid) {
        float inv = inv_deg[r * NN + n];
        int4 o;
        o.x = (int)((unsigned int)f2bf(a0 * inv) | ((unsigned int)f2bf(a1 * inv) << 16));
        o.y = (int)((unsigned int)f2bf(a2 * inv) | ((unsigned int)f2bf(a3 * inv) << 16));
        o.z = (int)((unsigned int)f2bf(a4 * inv) | ((unsigned int)f2bf(a5 * inv) << 16));
        o.w = (int)((unsigned int)f2bf(a6 * inv) | ((unsigned int)f2bf(a7 * inv) << 16));
        *(int4*)(z + (size_t)n * 192 + ks * 64 + sub * 8) = o;
    }
}

// ---------------- fused layer-0 (merged A+B): y=0 dstA, y=1 dstB ----------------
__global__ __launch_bounds__(256) void layer0_kernel(
    const ushort* __restrict__ eA, const ushort* __restrict__ eB,
    const int* __restrict__ row_ptr, const int* __restrict__ col_idx,
    const float* __restrict__ inv_deg, const int* __restrict__ perm,
    const float* __restrict__ bias, ushort* __restrict__ hA, ushort* __restrict__ hB)
{
    int side = blockIdx.y;
    const int relT[2][3] = { {1, 2, 5}, {0, 3, 4} };
    int tid = threadIdx.x;
    int wid = tid >> 6, lane = tid & 63;
    int grp = lane >> 3, sub = lane & 7;
    int idx = blockIdx.x * 32 + wid * 8 + grp;
    bool valid = (idx < NN);
    int n = valid ? perm[(6 + side) * NN + idx] : 0;
    float acc[8];
    {
        float4 b0 = *(const float4*)(bias + sub * 8);
        float4 b1 = *(const float4*)(bias + sub * 8 + 4);
        acc[0] = b0.x; acc[1] = b0.y; acc[2] = b0.z; acc[3] = b0.w;
        acc[4] = b1.x; acc[5] = b1.y; acc[6] = b1.z; acc[7] = b1.w;
    }
    #pragma unroll
    for (int ks = 0; ks < 3; ++ks) {
        int r = relT[side][ks];
        // srcs: side0 {B,A,B}, side1 {A,B,A}  -> src is A when (side==0)==(ks==1)
        const ushort* F = ((side == 0) == (ks == 1)) ? eA : eB;
        const int* rp = row_ptr + r * (NN + 1);
        const int* ci = col_idx + (size_t)r * EE;
        int s = valid ? rp[n] : 0;
        int e = valid ? rp[n + 1] : 0;
        float a0 = 0.f, a1 = 0.f, a2 = 0.f, a3 = 0.f, a4 = 0.f, a5 = 0.f, a6 = 0.f, a7 = 0.f;
        int t = s;
        for (; t + 2 <= e; t += 2) {
            int c0 = ci[t], c1 = ci[t + 1];
            int4 u = *(const int4*)(F + (size_t)c0 * DD + sub * 8);
            int4 w = *(const int4*)(F + (size_t)c1 * DD + sub * 8);
            float l, h;
            bfpair((unsigned int)u.x, l, h); a0 += l; a1 += h;
            bfpair((unsigned int)u.y, l, h); a2 += l; a3 += h;
            bfpair((unsigned int)u.z, l, h); a4 += l; a5 += h;
            bfpair((unsigned int)u.w, l, h); a6 += l; a7 += h;
            bfpair((unsigned int)w.x, l, h); a0 += l; a1 += h;
            bfpair((unsigned int)w.y, l, h); a2 += l; a3 += h;
            bfpair((unsigned int)w.z, l, h); a4 += l; a5 += h;
            bfpair((unsigned int)w.w, l, h); a6 += l; a7 += h;
        }
        if (t < e) {
            int c0 = ci[t];
            int4 u = *(const int4*)(F + (size_t)c0 * DD + sub * 8);
            float l, h;
            bfpair((unsigned int)u.x, l, h); a0 += l; a1 += h;
            bfpair((unsigned int)u.y, l, h); a2 += l; a3 += h;
            bfpair((unsigned int)u.z, l, h); a4 += l; a5 += h;
            bfpair((unsigned int)u.w, l, h); a6 += l; a7 += h;
        }
        float inv = valid ? inv_deg[r * NN + n] : 0.f;
        acc[0] += a0 * inv; acc[1] += a1 * inv; acc[2] += a2 * inv; acc[3] += a3 * inv;
        acc[4] += a4 * inv; acc[5] += a5 * inv; acc[6] += a6 * inv; acc[7] += a7 * inv;
    }
    if (valid) {
        ushort* h = side ? hB : hA;
        int4 o;
        o.x = (int)((unsigned int)f2bf(fmaxf(acc[0], 0.f)) | ((unsigned int)f2bf(fmaxf(acc[1], 0.f)) << 16));
        o.y = (int)((unsigned int)f2bf(fmaxf(acc[2], 0.f)) | ((unsigned int)f2bf(fmaxf(acc[3], 0.f)) << 16));
        o.z = (int)((unsigned int)f2bf(fmaxf(acc[4], 0.f)) | ((unsigned int)f2bf(fmaxf(acc[5], 0.f)) << 16));
        o.w = (int)((unsigned int)f2bf(fmaxf(acc[6], 0.f)) | ((unsigned int)f2bf(fmaxf(acc[7], 0.f)) << 16));
        *(int4*)(h + (size_t)n * DD + sub * 8) = o;
    }
}

// ---------------- layer-1 MFMA GEMM ----------------
__global__ __launch_bounds__(256) void gemm1_mfma_kernel(
    const ushort* __restrict__ A, const ushort* __restrict__ Wp,
    int r0, int r1, int r2, const float* __restrict__ bias, ushort* __restrict__ out)
{
    int tid = threadIdx.x;
    int wave = tid >> 6, lane = tid & 63;
    int q = lane & 15, p = lane >> 4;
    int n0 = blockIdx.x * 64 + wave * 16;
    int rr[3] = { r0, r1, r2 };
    f32x4 acc0 = {0.f, 0.f, 0.f, 0.f};
    f32x4 acc1 = {0.f, 0.f, 0.f, 0.f};
    f32x4 acc2 = {0.f, 0.f, 0.f, 0.f};
    f32x4 acc3 = {0.f, 0.f, 0.f, 0.f};
    const ushort* arow = A + (size_t)(n0 + q) * 192 + p * 8;
    #pragma unroll
    for (int ks = 0; ks < 3; ++ks) {
        int rel = rr[ks];
        #pragma unroll
        for (int t = 0; t < 2; ++t) {
            bf16x8 a = *(const bf16x8*)(arow + ks * 64 + t * 32);
            const ushort* wb = Wp + (((size_t)(rel * 8 + t * 4 + p) * 64 + q) << 3);
            bf16x8 b0 = *(const bf16x8*)(wb);
            bf16x8 b1 = *(const bf16x8*)(wb + 16 * 8);
            bf16x8 b2 = *(const bf16x8*)(wb + 32 * 8);
            bf16x8 b3 = *(const bf16x8*)(wb + 48 * 8);
            acc0 = __builtin_amdgcn_mfma_f32_16x16x32_bf16(a, b0, acc0, 0, 0, 0);
            acc1 = __builtin_amdgcn_mfma_f32_16x16x32_bf16(a, b1, acc1, 0, 0, 0);
            acc2 = __builtin_amdgcn_mfma_f32_16x16x32_bf16(a, b2, acc2, 0, 0, 0);
            acc3 = __builtin_amdgcn_mfma_f32_16x16x32_bf16(a, b3, acc3, 0, 0, 0);
        }
    }
    float bv0 = bias[q], bv1 = bias[16 + q], bv2 = bias[32 + q], bv3 = bias[48 + q];
    #pragma unroll
    for (int v = 0; v < 4; ++v) {
        int n = n0 + p * 4 + v;
        if (n < NN) {
            ushort* orow = out + (size_t)n * 64;
            orow[q]      = f2bf(fmaxf(acc0[v] + bv0, 0.f));
            orow[16 + q] = f2bf(fmaxf(acc1[v] + bv1, 0.f));
            orow[32 + q] = f2bf(fmaxf(acc2[v] + bv2, 0.f));
            orow[48 + q] = f2bf(fmaxf(acc3[v] + bv3, 0.f));
        }
    }
}

// ---------------- layer-2 MFMA GEMM ----------------
__global__ __launch_bounds__(256) void gemm2_mfma_kernel(
    const ushort* __restrict__ A, const ushort* __restrict__ Wp,
    int r0, int r1, int r2, const float* __restrict__ bias, float* __restrict__ out)
{
    int tid = threadIdx.x;
    int wave = tid >> 6, lane = tid & 63;
    int q = lane & 15, p = lane >> 4;
    int n0 = blockIdx.x * 64 + wave * 16;
    int rr[3] = { r0, r1, r2 };
    f32x4 acc = {0.f, 0.f, 0.f, 0.f};
    const ushort* arow = A + (size_t)(n0 + q) * 192 + p * 8;
    #pragma unroll
    for (int ks = 0; ks < 3; ++ks) {
        int rel = rr[ks];
        #pragma unroll
        for (int t = 0; t < 2; ++t) {
            bf16x8 a = *(const bf16x8*)(arow + ks * 64 + t * 32);
            bf16x8 b = *(const bf16x8*)(Wp + (((size_t)(rel * 8 + t * 4 + p) * 16 + q) << 3));
            acc = __builtin_amdgcn_mfma_f32_16x16x32_bf16(a, b, acc, 0, 0, 0);
        }
    }
    float bv = bias[q];
    #pragma unroll
    for (int v = 0; v < 4; ++v) {
        int n = n0 + p * 4 + v;
        if (n < NN) out[(size_t)n * 16 + q] = acc[v] + bv;
    }
}

extern "C" void kernel_launch(void* const* d_in, const int* in_sizes, int n_in,
                              void* d_out, int out_size, void* d_ws, size_t ws_size,
                              hipStream_t stream)
{
    const float* embA  = (const float*)d_in[0];
    const float* embB  = (const float*)d_in[1];
    const float* bias0 = (const float*)d_in[2];
    const float* wc1   = (const float*)d_in[3];
    const float* b1    = (const float*)d_in[4];
    const float* bias1 = (const float*)d_in[5];
    const float* wc2   = (const float*)d_in[6];
    const float* b2    = (const float*)d_in[7];
    const float* bias2 = (const float*)d_in[8];

    Edges ep;
    for (int r = 0; r < NR; ++r) {
        ep.src[r] = (const int*)d_in[9 + 2 * r];
        ep.dst[r] = (const int*)d_in[10 + 2 * r];
    }

    char* ws = (char*)d_ws;
    size_t off = 0;
    auto alloc = [&](size_t bytes) {
        void* p = ws + off;
        off = (off + bytes + 255) & ~(size_t)255;
        return p;
    };
    ushort* Wp1     = (ushort*)alloc((size_t)NR * 8 * 64 * 8 * 2);
    ushort* Wp2     = (ushort*)alloc((size_t)NR * 8 * 16 * 8 * 2);
    int*    cnt_mat = (int*)   alloc((size_t)NR * FLATN * 4);
    int*    off_fl  = (int*)   alloc((size_t)NR * FLATN * 4);
    int*    bbase   = (int*)   alloc((size_t)NR * (NBK + 1) * 4);
    int*    row_ptr = (int*)   alloc((size_t)NR * (NN + 1) * 4);
    float*  inv_deg = (float*) alloc((size_t)NR * NN * 4);
    int*    col_idx = (int*)   alloc((size_t)NR * EE * 4);
    int*    perm    = (int*)   alloc((size_t)NVR * NN * 4);
    ushort* zA      = (ushort*)alloc((size_t)NN * 192 * 2);
    ushort* zB      = (ushort*)alloc((size_t)NN * 192 * 2);
    ushort* h0A     = (ushort*)alloc((size_t)NN * DD * 2);
    ushort* h0B     = (ushort*)alloc((size_t)NN * DD * 2);
    ushort* h1A     = (ushort*)alloc((size_t)NN * DD * 2);
    ushort* h1B     = (ushort*)alloc((size_t)NN * DD * 2);
    (void)ws_size;

    // lifetime-disjoint aliases:
    unsigned int* ebuf   = (unsigned int*)zA;   // before first agg write to zA
    ushort*       embA16 = h1A;                 // during layer-0 only
    ushort*       embB16 = h1B;
    int*          cnt2   = cnt_mat;             // NVR*FLAT2*4 = 256KB <= NR*FLATN*4 (301KB)
    int*          off2   = off_fl;              // both dead after csr_fine

    int nw = NR * DD * DD + NR * DD * OD;
    build_w_kernel<<<(nw + 255) / 256, 256, 0, stream>>>(wc1, b1, wc2, b2, Wp1, Wp2);
    cvt_kernel<<<(NN * DD / 4 + 255) / 256, 256, 0, stream>>>(embA, embA16, NN * DD / 4);
    cvt_kernel<<<(NN * DD / 4 + 255) / 256, 256, 0, stream>>>(embB, embB16, NN * DD / 4);

    count_kernel<<<dim3(SBLK, NR), 256, 0, stream>>>(ep, cnt_mat);
    flat_scan_kernel<<<NR, 1024, 0, stream>>>(cnt_mat, off_fl, bbase);
    scatter2_kernel<<<dim3(SBLK, NR), 256, 0, stream>>>(ep, off_fl, ebuf);
    csr_fine_kernel<<<dim3(NBK, NR), 256, 0, stream>>>(ebuf, bbase, row_ptr, inv_deg, col_idx);

    // degree-sorted processing orders (8 virtual relations)
    dhist_kernel<<<dim3(DBLK, NVR), 256, 0, stream>>>(row_ptr, cnt2);
    dscan_kernel<<<NVR, 1024, 0, stream>>>(cnt2, off2);
    dscatter_kernel<<<dim3(DBLK, NVR), 256, 0, stream>>>(row_ptr, off2, perm);

    int agx = (NN + 31) / 32;
    int ggrid = (NN + 63) / 64;
    // relations: r0 A->B, r1 B->A, r2 A->A, r3 B->B, r4 A->B, r5 B->A
    // dst A: rels {1,2,5} srcs {B,A,B};  dst B: rels {0,3,4} srcs {A,B,A}

    // layer 0 (fused, both sides in one launch)
    layer0_kernel<<<dim3(agx, 2), 256, 0, stream>>>(
        embA16, embB16, row_ptr, col_idx, inv_deg, perm, bias0, h0A, h0B);

    // layer 1: all 6 (dst, rel) slots in one launch
    agg_kernel<<<dim3(agx, 6), 256, 0, stream>>>(
        h0A, h0B, row_ptr, col_idx, inv_deg, perm, zA, zB);
    gemm1_mfma_kernel<<<ggrid, 256, 0, stream>>>(zA, Wp1, 1, 2, 5, bias1, h1A);
    gemm1_mfma_kernel<<<ggrid, 256, 0, stream>>>(zB, Wp1, 0, 3, 4, bias1, h1B);

    // layer 2 (dst A only): slots y=0..2
    agg_kernel<<<dim3(agx, 3), 256, 0, stream>>>(
        h1A, h1B, row_ptr, col_idx, inv_deg, perm, zA, zB);
    gemm2_mfma_kernel<<<ggrid, 256, 0, stream>>>(zA, Wp2, 1, 2, 5, bias2, (float*)d_out);
}

// Round 10
// 303.116 us; speedup vs baseline: 1.4236x; 1.0250x over previous
//
#include <hip/hip_runtime.h>

#define NN 100000
#define EE 500000
#define DD 64
#define OD 16
#define NR 6
#define NBASE 4
#define BSH 10
#define NBK 98         /* ceil(NN / 1024) */
#define SBLK 128       /* scatter blocks per relation */
#define FLATN (NBK * SBLK)   /* 12544 */
#define STCAP 5632     /* fine-bucket edge capacity */
#define DBIN 64        /* degree-sort bins */
#define NVR 8          /* 6 per-rel orders + 2 sum-degree orders */

struct Edges { const int* src[NR]; const int* dst[NR]; };

typedef __attribute__((ext_vector_type(8))) short bf16x8;
typedef __attribute__((ext_vector_type(4))) float f32x4;

__device__ __forceinline__ float bf2f(ushort u) {
    union { unsigned int i; float f; } v; v.i = ((unsigned int)u) << 16; return v.f;
}
__device__ __forceinline__ ushort f2bf(float f) {
    unsigned int x = __float_as_uint(f);
    unsigned int r = (x + 0x7fffu + ((x >> 16) & 1u)) >> 16;
    return (ushort)r;
}
__device__ __forceinline__ void bfpair(unsigned int u, float& lo, float& hi) {
    lo = __uint_as_float(u << 16);
    hi = __uint_as_float(u & 0xffff0000u);
}
__device__ __forceinline__ void acc8(const int4& u, float* a) {
    float l, h;
    bfpair((unsigned int)u.x, l, h); a[0] += l; a[1] += h;
    bfpair((unsigned int)u.y, l, h); a[2] += l; a[3] += h;
    bfpair((unsigned int)u.z, l, h); a[4] += l; a[5] += h;
    bfpair((unsigned int)u.w, l, h); a[6] += l; a[7] += h;
}

// ---------------- W = einsum('rb,bio->rio'), emitted bf16 B-fragment-packed ----------------
__global__ __launch_bounds__(256) void build_w_kernel(
    const float* __restrict__ wc1, const float* __restrict__ b1,
    const float* __restrict__ wc2, const float* __restrict__ b2,
    ushort* __restrict__ Wp1, ushort* __restrict__ Wp2)
{
    int idx = blockIdx.x * blockDim.x + threadIdx.x;
    const int n1 = NR * DD * DD;
    const int n2 = NR * DD * OD;
    if (idx < n1) {
        int r = idx >> 12, rem = idx & 4095;
        int i = rem >> 6, o = rem & 63;
        float s = 0.f;
        #pragma unroll
        for (int b = 0; b < NBASE; ++b) s += wc1[r * NBASE + b] * b1[b * 4096 + rem];
        Wp1[(((size_t)(r * 8 + (i >> 3)) * 64 + o) << 3) + (i & 7)] = f2bf(s);
    } else if (idx < n1 + n2) {
        int j = idx - n1;
        int r = j >> 10, rem = j & 1023;
        int i = rem >> 4, o = rem & 15;
        float s = 0.f;
        #pragma unroll
        for (int b = 0; b < NBASE; ++b) s += wc2[r * NBASE + b] * b2[b * 1024 + rem];
        Wp2[(((size_t)(r * 8 + (i >> 3)) * 16 + o) << 3) + (i & 7)] = f2bf(s);
    }
}

// ---------------- f32 -> bf16 embedding conversion (both tables, y=0/1) ----------------
__global__ __launch_bounds__(256) void cvt_kernel(
    const float* __restrict__ inA, const float* __restrict__ inB,
    ushort* __restrict__ outA, ushort* __restrict__ outB, int n4)
{
    int i = blockIdx.x * 256 + threadIdx.x;
    if (i >= n4) return;
    const float* in = blockIdx.y ? inB : inA;
    ushort* out = blockIdx.y ? outB : outA;
    float4 v = ((const float4*)in)[i];
    ushort4 o;
    o.x = f2bf(v.x); o.y = f2bf(v.y); o.z = f2bf(v.z); o.w = f2bf(v.w);
    ((ushort4*)out)[i] = o;
}

// ---------------- CSR build: pass A — per-(block,bucket) counts ----------------
__global__ __launch_bounds__(256) void count_kernel(Edges ep, int* __restrict__ cnt_mat)
{
    __shared__ int h[NBK];
    int r = blockIdx.y, blk = blockIdx.x;
    const int* __restrict__ dst = ep.dst[r];
    const int chunk = (EE + SBLK - 1) / SBLK;
    int e0 = blk * chunk, e1 = min(e0 + chunk, EE);
    for (int i = threadIdx.x; i < NBK; i += 256) h[i] = 0;
    __syncthreads();
    for (int e = e0 + threadIdx.x; e < e1; e += 256)
        atomicAdd(&h[dst[e] >> BSH], 1);
    __syncthreads();
    for (int b = threadIdx.x; b < NBK; b += 256)
        cnt_mat[r * FLATN + b * SBLK + blk] = h[b];
}

// ---------------- pass B — flat exclusive scan over (bucket, block) per rel ----------------
__global__ __launch_bounds__(1024) void flat_scan_kernel(
    const int* __restrict__ cnt_mat, int* __restrict__ off_flat, int* __restrict__ bbase)
{
    __shared__ int wsum[16];
    const int TPE = 13;
    int r = blockIdx.x;
    int tid = threadIdx.x, lane = tid & 63, wid = tid >> 6;
    int base = tid * TPE;
    int v[TPE];
    int s = 0;
    #pragma unroll
    for (int j = 0; j < TPE; ++j) {
        int i = base + j;
        v[j] = (i < FLATN) ? cnt_mat[r * FLATN + i] : 0;
        s += v[j];
    }
    int si = s;
    #pragma unroll
    for (int off = 1; off < 64; off <<= 1) {
        int t = __shfl_up(si, off);
        if (lane >= off) si += t;
    }
    if (lane == 63) wsum[wid] = si;
    __syncthreads();
    if (wid == 0) {
        int ws = (lane < 16) ? wsum[lane] : 0;
        #pragma unroll
        for (int off = 1; off < 16; off <<= 1) {
            int t = __shfl_up(ws, off);
            if (lane >= off) ws += t;
        }
        if (lane < 16) wsum[lane] = ws;
    }
    __syncthreads();
    int texcl = (wid > 0 ? wsum[wid - 1] : 0) + (si - s);
    int part = 0;
    #pragma unroll
    for (int j = 0; j < TPE; ++j) {
        int i = base + j;
        if (i < FLATN) {
            int o = texcl + part;
            off_flat[r * FLATN + i] = o;
            if ((i & (SBLK - 1)) == 0) bbase[r * (NBK + 1) + (i >> 7)] = o;
        }
        part += v[j];
    }
    if (tid == 0) bbase[r * (NBK + 1) + NBK] = EE;
}

// ---------------- pass C — scatter with precomputed cursors ----------------
__global__ __launch_bounds__(256) void scatter2_kernel(
    Edges ep, const int* __restrict__ off_flat, unsigned int* __restrict__ ebuf)
{
    __shared__ int goff[NBK];
    __shared__ int lcnt[NBK];
    int r = blockIdx.y, blk = blockIdx.x;
    const int* __restrict__ src = ep.src[r];
    const int* __restrict__ dst = ep.dst[r];
    unsigned int* eb = ebuf + (size_t)r * EE;
    const int chunk = (EE + SBLK - 1) / SBLK;
    int e0 = blk * chunk, e1 = min(e0 + chunk, EE);
    if (threadIdx.x < NBK) {
        goff[threadIdx.x] = off_flat[r * FLATN + threadIdx.x * SBLK + blk];
        lcnt[threadIdx.x] = 0;
    }
    __syncthreads();
    for (int e = e0 + threadIdx.x; e < e1; e += 256) {
        int d = dst[e];
        int b = d >> BSH;
        int pos = goff[b] + atomicAdd(&lcnt[b], 1);
        eb[pos] = (unsigned int)src[e] | ((unsigned int)(d & 1023) << 17);
    }
}

// ---------------- pass D — per-(bucket,rel) fine CSR ----------------
__global__ __launch_bounds__(256) void csr_fine_kernel(
    const unsigned int* __restrict__ ebuf, const int* __restrict__ bbase,
    int* __restrict__ row_ptr, float* __restrict__ inv_deg, int* __restrict__ col_idx)
{
    __shared__ int nh[1024];
    __shared__ int nb[1024];
    __shared__ int wsum4[4];
    __shared__ int stage[STCAP];
    int r = blockIdx.y, b = blockIdx.x;
    int tid = threadIdx.x, lane = tid & 63, wid = tid >> 6;
    int gb = bbase[r * (NBK + 1) + b];
    int ge = bbase[r * (NBK + 1) + b + 1];
    int cnt = ge - gb;
    if (cnt > STCAP) cnt = STCAP;
    const unsigned int* eb = ebuf + (size_t)r * EE + gb;
    #pragma unroll
    for (int j = 0; j < 4; ++j) nh[tid * 4 + j] = 0;
    __syncthreads();
    for (int i = tid; i < cnt; i += 256)
        atomicAdd(&nh[(eb[i] >> 17) & 1023], 1);
    __syncthreads();
    int v0 = nh[tid * 4 + 0], v1 = nh[tid * 4 + 1], v2 = nh[tid * 4 + 2], v3 = nh[tid * 4 + 3];
    int s = v0 + v1 + v2 + v3;
    int si = s;
    #pragma unroll
    for (int off = 1; off < 64; off <<= 1) {
        int t = __shfl_up(si, off);
        if (lane >= off) si += t;
    }
    if (lane == 63) wsum4[wid] = si;
    __syncthreads();
    if (tid == 0) {
        int a = 0;
        #pragma unroll
        for (int k = 0; k < 4; ++k) { int t = wsum4[k]; wsum4[k] = a; a += t; }
    }
    __syncthreads();
    int texcl = wsum4[wid] + (si - s);
    int p0 = texcl, p1 = p0 + v0, p2 = p1 + v1, p3 = p2 + v2;
    nb[tid * 4 + 0] = p0; nb[tid * 4 + 1] = p1; nb[tid * 4 + 2] = p2; nb[tid * 4 + 3] = p3;
    {
        int node0 = b * 1024 + tid * 4;
        int pj[4] = { p0, p1, p2, p3 };
        int vj[4] = { v0, v1, v2, v3 };
        #pragma unroll
        for (int j = 0; j < 4; ++j) {
            int node = node0 + j;
            if (node < NN) {
                row_ptr[r * (NN + 1) + node] = gb + pj[j];
                inv_deg[r * NN + node] = 1.0f / (float)(vj[j] > 1 ? vj[j] : 1);
            }
        }
    }
    if (b == NBK - 1 && tid == 0) row_ptr[r * (NN + 1) + NN] = EE;
    #pragma unroll
    for (int j = 0; j < 4; ++j) nh[tid * 4 + j] = 0;
    __syncthreads();
    for (int i = tid; i < cnt; i += 256) {
        unsigned int w = eb[i];
        int loc = (w >> 17) & 1023;
        int pos = nb[loc] + atomicAdd(&nh[loc], 1);
        stage[pos] = (int)(w & 0x1ffffu);
    }
    __syncthreads();
    int* co = col_idx + (size_t)r * EE + gb;
    for (int i = tid; i < cnt; i += 256) co[i] = stage[i];
}

// ---------------- bucket-local degree sort ----------------
__device__ __forceinline__ int vdeg(int vr, int n, const int* __restrict__ rp)
{
    if (vr < 6) return rp[vr * (NN + 1) + n + 1] - rp[vr * (NN + 1) + n];
    if (vr == 6)
        return (rp[1 * (NN + 1) + n + 1] - rp[1 * (NN + 1) + n])
             + (rp[2 * (NN + 1) + n + 1] - rp[2 * (NN + 1) + n])
             + (rp[5 * (NN + 1) + n + 1] - rp[5 * (NN + 1) + n]);
    return (rp[0 * (NN + 1) + n + 1] - rp[0 * (NN + 1) + n])
         + (rp[3 * (NN + 1) + n + 1] - rp[3 * (NN + 1) + n])
         + (rp[4 * (NN + 1) + n + 1] - rp[4 * (NN + 1) + n]);
}

// block = (bucket b, vrel): degree-sort the <=1024 nodes of the bucket in-place order
__global__ __launch_bounds__(256) void bsort_kernel(
    const int* __restrict__ row_ptr, int* __restrict__ perm)
{
    __shared__ int h[DBIN];
    __shared__ int base_[DBIN];
    int vr = blockIdx.y, b = blockIdx.x;
    int n0 = b * 1024;
    int cnt = min(1024, NN - n0);
    int tid = threadIdx.x;
    if (tid < DBIN) h[tid] = 0;
    __syncthreads();
    int bin[4];
    #pragma unroll
    for (int j = 0; j < 4; ++j) {
        int i = tid + j * 256;
        if (i < cnt) {
            bin[j] = min(vdeg(vr, n0 + i, row_ptr), DBIN - 1);
            atomicAdd(&h[bin[j]], 1);
        } else bin[j] = -1;
    }
    __syncthreads();
    if (tid < 64) {
        int v = h[tid];
        int s = v;
        #pragma unroll
        for (int off = 1; off < 64; off <<= 1) {
            int t = __shfl_up(s, off);
            if (tid >= off) s += t;
        }
        base_[tid] = s - v;
        h[tid] = 0;   // reuse as cursor
    }
    __syncthreads();
    #pragma unroll
    for (int j = 0; j < 4; ++j) {
        if (bin[j] >= 0) {
            int pos = base_[bin[j]] + atomicAdd(&h[bin[j]], 1);
            perm[vr * NN + n0 + pos] = n0 + tid + j * 256;
        }
    }
}

// ---------------- merged aggregation (layers 1/2) ----------------
// y<3: dst A, rels {1,2,5}, srcs {B,A,B}, out zA; y>=3: dst B, rels {0,3,4}, srcs {A,B,A}, out zB
__global__ __launch_bounds__(256) void agg_kernel(
    const ushort* __restrict__ hA, const ushort* __restrict__ hB,
    const int* __restrict__ row_ptr, const int* __restrict__ col_idx,
    const float* __restrict__ inv_deg, const int* __restrict__ perm,
    ushort* __restrict__ zA, ushort* __restrict__ zB)
{
    const int relT[6]   = {1, 2, 5, 0, 3, 4};
    const int srcIsA[6] = {0, 1, 0, 1, 0, 1};
    int y = blockIdx.y;
    int r = relT[y];
    const ushort* F = srcIsA[y] ? hA : hB;
    ushort* z = (y < 3) ? zA : zB;
    int ks = (y < 3) ? y : y - 3;
    int tid = threadIdx.x;
    int wid = tid >> 6, lane = tid & 63;
    int grp = lane >> 3, sub = lane & 7;
    int idx = blockIdx.x * 32 + wid * 8 + grp;
    bool valid = (idx < NN);
    int n = valid ? perm[r * NN + idx] : 0;
    const int* rp = row_ptr + r * (NN + 1);
    const int* ci = col_idx + (size_t)r * EE;
    int s = valid ? rp[n] : 0;
    int e = valid ? rp[n + 1] : 0;
    float a[8] = {0.f, 0.f, 0.f, 0.f, 0.f, 0.f, 0.f, 0.f};
    int t = s;
    for (; t + 4 <= e; t += 4) {
        int c0 = ci[t], c1 = ci[t + 1], c2 = ci[t + 2], c3 = ci[t + 3];
        int4 u0 = *(const int4*)(F + (size_t)c0 * DD + sub * 8);
        int4 u1 = *(const int4*)(F + (size_t)c1 * DD + sub * 8);
        int4 u2 = *(const int4*)(F + (size_t)c2 * DD + sub * 8);
        int4 u3 = *(const int4*)(F + (size_t)c3 * DD + sub * 8);
        acc8(u0, a); acc8(u1, a); acc8(u2, a); acc8(u3, a);
    }
    for (; t < e; ++t) {
        int4 u = *(const int4*)(F + (size_t)ci[t] * DD + sub * 8);
        acc8(u, a);
    }
    if (valid) {
        float inv = inv_deg[r * NN + n];
        int4 o;
        o.x = (int)((unsigned int)f2bf(a[0] * inv) | ((unsigned int)f2bf(a[1] * inv) << 16));
        o.y = (int)((unsigned int)f2bf(a[2] * inv) | ((unsigned int)f2bf(a[3] * inv) << 16));
        o.z = (int)((unsigned int)f2bf(a[4] * inv) | ((unsigned int)f2bf(a[5] * inv) << 16));
        o.w = (int)((unsigned int)f2bf(a[6] * inv) | ((unsigned int)f2bf(a[7] * inv) << 16));
        *(int4*)(z + (size_t)n * 192 + ks * 64 + sub * 8) = o;
    }
}

// ---------------- fused layer-0 (merged A+B): y=0 dstA, y=1 dstB ----------------
__global__ __launch_bounds__(256) void layer0_kernel(
    const ushort* __restrict__ eA, const ushort* __restrict__ eB,
    const int* __restrict__ row_ptr, const int* __restrict__ col_idx,
    const float* __restrict__ inv_deg, const int* __restrict__ perm,
    const float* __restrict__ bias, ushort* __restrict__ hA, ushort* __restrict__ hB)
{
    int side = blockIdx.y;
    const int relT[2][3] = { {1, 2, 5}, {0, 3, 4} };
    int tid = threadIdx.x;
    int wid = tid >> 6, lane = tid & 63;
    int grp = lane >> 3, sub = lane & 7;
    int idx = blockIdx.x * 32 + wid * 8 + grp;
    bool valid = (idx < NN);
    int n = valid ? perm[(6 + side) * NN + idx] : 0;
    float acc[8];
    {
        float4 b0 = *(const float4*)(bias + sub * 8);
        float4 b1 = *(const float4*)(bias + sub * 8 + 4);
        acc[0] = b0.x; acc[1] = b0.y; acc[2] = b0.z; acc[3] = b0.w;
        acc[4] = b1.x; acc[5] = b1.y; acc[6] = b1.z; acc[7] = b1.w;
    }
    #pragma unroll
    for (int ks = 0; ks < 3; ++ks) {
        int r = relT[side][ks];
        const ushort* F = ((side == 0) == (ks == 1)) ? eA : eB;
        const int* rp = row_ptr + r * (NN + 1);
        const int* ci = col_idx + (size_t)r * EE;
        int s = valid ? rp[n] : 0;
        int e = valid ? rp[n + 1] : 0;
        float a[8] = {0.f, 0.f, 0.f, 0.f, 0.f, 0.f, 0.f, 0.f};
        int t = s;
        for (; t + 4 <= e; t += 4) {
            int c0 = ci[t], c1 = ci[t + 1], c2 = ci[t + 2], c3 = ci[t + 3];
            int4 u0 = *(const int4*)(F + (size_t)c0 * DD + sub * 8);
            int4 u1 = *(const int4*)(F + (size_t)c1 * DD + sub * 8);
            int4 u2 = *(const int4*)(F + (size_t)c2 * DD + sub * 8);
            int4 u3 = *(const int4*)(F + (size_t)c3 * DD + sub * 8);
            acc8(u0, a); acc8(u1, a); acc8(u2, a); acc8(u3, a);
        }
        for (; t < e; ++t) {
            int4 u = *(const int4*)(F + (size_t)ci[t] * DD + sub * 8);
            acc8(u, a);
        }
        float inv = valid ? inv_deg[r * NN + n] : 0.f;
        #pragma unroll
        for (int j = 0; j < 8; ++j) acc[j] += a[j] * inv;
    }
    if (valid) {
        ushort* h = side ? hB : hA;
        int4 o;
        o.x = (int)((unsigned int)f2bf(fmaxf(acc[0], 0.f)) | ((unsigned int)f2bf(fmaxf(acc[1], 0.f)) << 16));
        o.y = (int)((unsigned int)f2bf(fmaxf(acc[2], 0.f)) | ((unsigned int)f2bf(fmaxf(acc[3], 0.f)) << 16));
        o.z = (int)((unsigned int)f2bf(fmaxf(acc[4], 0.f)) | ((unsigned int)f2bf(fmaxf(acc[5], 0.f)) << 16));
        o.w = (int)((unsigned int)f2bf(fmaxf(acc[6], 0.f)) | ((unsigned int)f2bf(fmaxf(acc[7], 0.f)) << 16));
        *(int4*)(h + (size_t)n * DD + sub * 8) = o;
    }
}

// ---------------- layer-1 MFMA GEMM (both sides, y=0/1) ----------------
__global__ __launch_bounds__(256) void gemm1_mfma_kernel(
    const ushort* __restrict__ zA, const ushort* __restrict__ zB,
    const ushort* __restrict__ Wp, const float* __restrict__ bias,
    ushort* __restrict__ hA, ushort* __restrict__ hB)
{
    const int relT[2][3] = { {1, 2, 5}, {0, 3, 4} };
    int y = blockIdx.y;
    const ushort* A = y ? zB : zA;
    ushort* out = y ? hB : hA;
    int tid = threadIdx.x;
    int wave = tid >> 6, lane = tid & 63;
    int q = lane & 15, p = lane >> 4;
    int n0 = blockIdx.x * 64 + wave * 16;
    f32x4 acc0 = {0.f, 0.f, 0.f, 0.f};
    f32x4 acc1 = {0.f, 0.f, 0.f, 0.f};
    f32x4 acc2 = {0.f, 0.f, 0.f, 0.f};
    f32x4 acc3 = {0.f, 0.f, 0.f, 0.f};
    const ushort* arow = A + (size_t)(n0 + q) * 192 + p * 8;
    #pragma unroll
    for (int ks = 0; ks < 3; ++ks) {
        int rel = relT[y][ks];
        #pragma unroll
        for (int t = 0; t < 2; ++t) {
            bf16x8 a = *(const bf16x8*)(arow + ks * 64 + t * 32);
            const ushort* wb = Wp + (((size_t)(rel * 8 + t * 4 + p) * 64 + q) << 3);
            bf16x8 b0 = *(const bf16x8*)(wb);
            bf16x8 b1 = *(const bf16x8*)(wb + 16 * 8);
            bf16x8 b2 = *(const bf16x8*)(wb + 32 * 8);
            bf16x8 b3 = *(const bf16x8*)(wb + 48 * 8);
            acc0 = __builtin_amdgcn_mfma_f32_16x16x32_bf16(a, b0, acc0, 0, 0, 0);
            acc1 = __builtin_amdgcn_mfma_f32_16x16x32_bf16(a, b1, acc1, 0, 0, 0);
            acc2 = __builtin_amdgcn_mfma_f32_16x16x32_bf16(a, b2, acc2, 0, 0, 0);
            acc3 = __builtin_amdgcn_mfma_f32_16x16x32_bf16(a, b3, acc3, 0, 0, 0);
        }
    }
    float bv0 = bias[q], bv1 = bias[16 + q], bv2 = bias[32 + q], bv3 = bias[48 + q];
    #pragma unroll
    for (int v = 0; v < 4; ++v) {
        int n = n0 + p * 4 + v;
        if (n < NN) {
            ushort* orow = out + (size_t)n * 64;
            orow[q]      = f2bf(fmaxf(acc0[v] + bv0, 0.f));
            orow[16 + q] = f2bf(fmaxf(acc1[v] + bv1, 0.f));
            orow[32 + q] = f2bf(fmaxf(acc2[v] + bv2, 0.f));
            orow[48 + q] = f2bf(fmaxf(acc3[v] + bv3, 0.f));
        }
    }
}

// ---------------- layer-2 MFMA GEMM ----------------
__global__ __launch_bounds__(256) void gemm2_mfma_kernel(
    const ushort* __restrict__ A, const ushort* __restrict__ Wp,
    int r0, int r1, int r2, const float* __restrict__ bias, float* __restrict__ out)
{
    int tid = threadIdx.x;
    int wave = tid >> 6, lane = tid & 63;
    int q = lane & 15, p = lane >> 4;
    int n0 = blockIdx.x * 64 + wave * 16;
    int rr[3] = { r0, r1, r2 };
    f32x4 acc = {0.f, 0.f, 0.f, 0.f};
    const ushort* arow = A + (size_t)(n0 + q) * 192 + p * 8;
    #pragma unroll
    for (int ks = 0; ks < 3; ++ks) {
        int rel = rr[ks];
        #pragma unroll
        for (int t = 0; t < 2; ++t) {
            bf16x8 a = *(const bf16x8*)(arow + ks * 64 + t * 32);
            bf16x8 b = *(const bf16x8*)(Wp + (((size_t)(rel * 8 + t * 4 + p) * 16 + q) << 3));
            acc = __builtin_amdgcn_mfma_f32_16x16x32_bf16(a, b, acc, 0, 0, 0);
        }
    }
    float bv = bias[q];
    #pragma unroll
    for (int v = 0; v < 4; ++v) {
        int n = n0 + p * 4 + v;
        if (n < NN) out[(size_t)n * 16 + q] = acc[v] + bv;
    }
}

extern "C" void kernel_launch(void* const* d_in, const int* in_sizes, int n_in,
                              void* d_out, int out_size, void* d_ws, size_t ws_size,
                              hipStream_t stream)
{
    const float* embA  = (const float*)d_in[0];
    const float* embB  = (const float*)d_in[1];
    const float* bias0 = (const float*)d_in[2];
    const float* wc1   = (const float*)d_in[3];
    const float* b1    = (const float*)d_in[4];
    const float* bias1 = (const float*)d_in[5];
    const float* wc2   = (const float*)d_in[6];
    const float* b2    = (const float*)d_in[7];
    const float* bias2 = (const float*)d_in[8];

    Edges ep;
    for (int r = 0; r < NR; ++r) {
        ep.src[r] = (const int*)d_in[9 + 2 * r];
        ep.dst[r] = (const int*)d_in[10 + 2 * r];
    }

    char* ws = (char*)d_ws;
    size_t off = 0;
    auto alloc = [&](size_t bytes) {
        void* p = ws + off;
        off = (off + bytes + 255) & ~(size_t)255;
        return p;
    };
    ushort* Wp1     = (ushort*)alloc((size_t)NR * 8 * 64 * 8 * 2);
    ushort* Wp2     = (ushort*)alloc((size_t)NR * 8 * 16 * 8 * 2);
    int*    cnt_mat = (int*)   alloc((size_t)NR * FLATN * 4);
    int*    off_fl  = (int*)   alloc((size_t)NR * FLATN * 4);
    int*    bbase   = (int*)   alloc((size_t)NR * (NBK + 1) * 4);
    int*    row_ptr = (int*)   alloc((size_t)NR * (NN + 1) * 4);
    float*  inv_deg = (float*) alloc((size_t)NR * NN * 4);
    int*    col_idx = (int*)   alloc((size_t)NR * EE * 4);
    int*    perm    = (int*)   alloc((size_t)NVR * NN * 4);
    ushort* zA      = (ushort*)alloc((size_t)NN * 192 * 2);
    ushort* zB      = (ushort*)alloc((size_t)NN * 192 * 2);
    ushort* h0A     = (ushort*)alloc((size_t)NN * DD * 2);
    ushort* h0B     = (ushort*)alloc((size_t)NN * DD * 2);
    ushort* h1A     = (ushort*)alloc((size_t)NN * DD * 2);
    ushort* h1B     = (ushort*)alloc((size_t)NN * DD * 2);
    (void)ws_size;

    // lifetime-disjoint aliases:
    unsigned int* ebuf   = (unsigned int*)zA;   // before first agg write to zA
    ushort*       embA16 = h1A;                 // during layer-0 only
    ushort*       embB16 = h1B;

    int nw = NR * DD * DD + NR * DD * OD;
    build_w_kernel<<<(nw + 255) / 256, 256, 0, stream>>>(wc1, b1, wc2, b2, Wp1, Wp2);
    cvt_kernel<<<dim3((NN * DD / 4 + 255) / 256, 2), 256, 0, stream>>>(
        embA, embB, embA16, embB16, NN * DD / 4);

    count_kernel<<<dim3(SBLK, NR), 256, 0, stream>>>(ep, cnt_mat);
    flat_scan_kernel<<<NR, 1024, 0, stream>>>(cnt_mat, off_fl, bbase);
    scatter2_kernel<<<dim3(SBLK, NR), 256, 0, stream>>>(ep, off_fl, ebuf);
    csr_fine_kernel<<<dim3(NBK, NR), 256, 0, stream>>>(ebuf, bbase, row_ptr, inv_deg, col_idx);

    // bucket-local degree-sorted processing orders (8 virtual relations)
    bsort_kernel<<<dim3(NBK, NVR), 256, 0, stream>>>(row_ptr, perm);

    int agx = (NN + 31) / 32;
    int ggrid = (NN + 63) / 64;
    // relations: r0 A->B, r1 B->A, r2 A->A, r3 B->B, r4 A->B, r5 B->A
    // dst A: rels {1,2,5} srcs {B,A,B};  dst B: rels {0,3,4} srcs {A,B,A}

    // layer 0 (fused, both sides in one launch)
    layer0_kernel<<<dim3(agx, 2), 256, 0, stream>>>(
        embA16, embB16, row_ptr, col_idx, inv_deg, perm, bias0, h0A, h0B);

    // layer 1: all 6 (dst, rel) slots in one launch
    agg_kernel<<<dim3(agx, 6), 256, 0, stream>>>(
        h0A, h0B, row_ptr, col_idx, inv_deg, perm, zA, zB);
    gemm1_mfma_kernel<<<dim3(ggrid, 2), 256, 0, stream>>>(
        zA, zB, Wp1, bias1, h1A, h1B);

    // layer 2 (dst A only): slots y=0..2
    agg_kernel<<<dim3(agx, 3), 256, 0, stream>>>(
        h1A, h1B, row_ptr, col_idx, inv_deg, perm, zA, zB);
    gemm2_mfma_kernel<<<ggrid, 256, 0, stream>>>(zA, Wp2, 1, 2, 5, bias2, (float*)d_out);
}